// Round 1
// baseline (1285.649 us; speedup 1.0000x reference)
//
#include <hip/hip_runtime.h>
#include <hip/hip_fp16.h>

typedef unsigned short u16;
typedef __attribute__((ext_vector_type(8))) short short8;
typedef __attribute__((ext_vector_type(4))) float floatx4;

#define ATT_SCALE 0.08838834764831845f

__device__ __forceinline__ u16 f2bf(float f) {
  unsigned u = __float_as_uint(f);
  u += 0x7FFFu + ((u >> 16) & 1u);
  return (u16)(u >> 16);
}

__device__ __forceinline__ float wsum(float v) {
#pragma unroll
  for (int m = 32; m >= 1; m >>= 1) v += __shfl_xor(v, m);
  return v;
}
__device__ __forceinline__ float wmaxr(float v) {
#pragma unroll
  for (int m = 32; m >= 1; m >>= 1) v = fmaxf(v, __shfl_xor(v, m));
  return v;
}

// pack score (monotone f16) + key idx into one sortable u32
__device__ __forceinline__ unsigned pack_sc(float v, unsigned idx) {
  u16 hb = __half_as_ushort(__float2half(v));
  u16 mono = (hb & 0x8000) ? (u16)(~hb) : (u16)(hb | 0x8000);
  return ((unsigned)mono << 16) | idx;
}
__device__ __forceinline__ float unpack_sc(unsigned p) {
  u16 mono = (u16)(p >> 16);
  u16 hb = (mono & 0x8000) ? (u16)(mono & 0x7FFF) : (u16)(~mono);
  return __half2float(__ushort_as_half(hb));
}

// ---------------------------------------------------------------------------
// Generic bf16 MFMA GEMM: C[M,N] = epilogue(A[M,K] @ B^T[N,K] + bias)
// A row-major (lda), B stored [n][k] (ldb) unless BT: B raw [k][n] (ldb), k<Kb.
// EPI: 0 f32 alpha*acc+bias | 1 bf16 acc+bias | 2 bf16 gelu(acc+bias)
//      3 f32 add+acc+bias (residual) | 4 f32 alpha*acc | 5 bf16 acc+add(optional)
// ---------------------------------------------------------------------------
template <int EPI, bool BT>
__global__ __launch_bounds__(256) void gemm_k(
    const u16* __restrict__ A, int lda, long sA,
    const u16* __restrict__ B, int ldb, long sB, int Kb,
    const float* __restrict__ bias,
    const float* __restrict__ add, long sAdd,
    void* __restrict__ Cv, int ldc, long sC,
    int M, int N, int K, float alpha) {
  __shared__ u16 As[128][40];  // +8 pad: conflict-free b128 frag reads
  __shared__ u16 Bs[64][40];
  const int tid = threadIdx.x;
  const int m0 = blockIdx.x * 128, n0 = blockIdx.y * 64;
  const int bz = blockIdx.z;
  A += (long)bz * sA;
  B += (long)bz * sB;
  const int w = tid >> 6, lane = tid & 63;
  const int wr = w & 1, wc = w >> 1;
  const int lr = lane & 15, lk = (lane >> 4) * 8;
  floatx4 zf = {0.f, 0.f, 0.f, 0.f};
  floatx4 acc[4][2];
#pragma unroll
  for (int i = 0; i < 4; i++)
#pragma unroll
    for (int j = 0; j < 2; j++) acc[i][j] = zf;

  for (int k0 = 0; k0 < K; k0 += 32) {
#pragma unroll
    for (int t = 0; t < 2; t++) {
      int task = tid + t * 256;
      int r = task >> 2, k8 = (task & 3) * 8;
      short8 v = {0, 0, 0, 0, 0, 0, 0, 0};
      if (m0 + r < M) v = *(const short8*)(A + (long)(m0 + r) * lda + k0 + k8);
      *(short8*)&As[r][k8] = v;
    }
    if (!BT) {
      int r = tid >> 2, k8 = (tid & 3) * 8;
      short8 v = {0, 0, 0, 0, 0, 0, 0, 0};
      if (n0 + r < N) v = *(const short8*)(B + (long)(n0 + r) * ldb + k0 + k8);
      *(short8*)&Bs[r][k8] = v;
    } else {
#pragma unroll
      for (int t = 0; t < 8; t++) {
        int task = tid + t * 256;
        int n = task & 63, kk = task >> 6;
        u16 v = 0;
        if (k0 + kk < Kb && n0 + n < N) v = B[(long)(k0 + kk) * ldb + n0 + n];
        Bs[n][kk] = v;
      }
    }
    __syncthreads();
    short8 af[4], bfr[2];
#pragma unroll
    for (int i = 0; i < 4; i++) af[i] = *(const short8*)&As[wr * 64 + i * 16 + lr][lk];
#pragma unroll
    for (int j = 0; j < 2; j++) bfr[j] = *(const short8*)&Bs[wc * 32 + j * 16 + lr][lk];
#pragma unroll
    for (int i = 0; i < 4; i++)
#pragma unroll
      for (int j = 0; j < 2; j++)
        acc[i][j] = __builtin_amdgcn_mfma_f32_16x16x32_bf16(af[i], bfr[j], acc[i][j], 0, 0, 0);
    __syncthreads();
  }
#pragma unroll
  for (int i = 0; i < 4; i++) {
#pragma unroll
    for (int j = 0; j < 2; j++) {
      int gn = n0 + wc * 32 + j * 16 + lr;
#pragma unroll
      for (int r = 0; r < 4; r++) {
        int gm = m0 + wr * 64 + i * 16 + (lane >> 4) * 4 + r;
        if (gm < M && gn < N) {
          float v = acc[i][j][r];
          float bi = bias ? bias[gn] : 0.f;
          long co = (long)bz * sC + (long)gm * ldc + gn;
          if (EPI == 0) {
            ((float*)Cv)[co] = v * alpha + bi;
          } else if (EPI == 1) {
            ((u16*)Cv)[co] = f2bf(v + bi);
          } else if (EPI == 2) {
            float t = v + bi;
            float g = 0.5f * t * (1.f + tanhf(0.7978845608028654f * (t + 0.044715f * t * t * t)));
            ((u16*)Cv)[co] = f2bf(g);
          } else if (EPI == 3) {
            ((float*)Cv)[co] = add[(long)gm * ldc + gn] + v + bi;
          } else if (EPI == 4) {
            ((float*)Cv)[co] = v * alpha;
          } else {
            float t = v + (add ? add[(long)bz * sAdd + (long)gm * ldc + gn] : 0.f);
            ((u16*)Cv)[co] = f2bf(t);
          }
        }
      }
    }
  }
}

// ---------------------------------------------------------------------------
// weight convert + transpose to bf16 [n][k] layouts
// layout in wbf (u16 elems): patchT@0 (128x768), qkvT@98304 (7x384x128),
// outT@442368 (7x128x128), ff1T@557056 (7x512x128), ff2T@1015808 (7x128x512)
// ---------------------------------------------------------------------------
__global__ __launch_bounds__(256) void cvtw_k(
    const float* __restrict__ pw, const float* __restrict__ qw,
    const float* __restrict__ ow, const float* __restrict__ f1,
    const float* __restrict__ f2, u16* __restrict__ wbf) {
  int idx = blockIdx.x * 256 + threadIdx.x;
  float v;
  if (idx < 98304) {
    int n = idx / 768, k = idx % 768;
    v = pw[k * 128 + n];
  } else if (idx < 442368) {
    int rel = idx - 98304;
    int i = rel / 49152, r = rel % 49152, n = r / 128, k = r % 128;
    v = qw[((long)i * 128 + k) * 384 + n];
  } else if (idx < 557056) {
    int rel = idx - 442368;
    int i = rel / 16384, r = rel % 16384, n = r / 128, k = r % 128;
    v = ow[((long)i * 128 + k) * 128 + n];
  } else if (idx < 1015808) {
    int rel = idx - 557056;
    int i = rel / 65536, r = rel % 65536, n = r / 128, k = r % 128;
    v = f1[((long)i * 128 + k) * 512 + n];
  } else {
    int rel = idx - 1015808;
    int i = rel / 65536, r = rel % 65536, n = r / 512, k = r % 512;
    v = f2[((long)i * 512 + k) * 128 + n];
  }
  wbf[idx] = f2bf(v);
}

// patchify x(32,3,224,224) -> p_bf(32,196,768) bf16
__global__ __launch_bounds__(256) void patchify_k(const float* __restrict__ x,
                                                  u16* __restrict__ p) {
  long idx = (long)blockIdx.x * 256 + threadIdx.x;  // 4,816,896 total
  int f = (int)(idx % 768);
  long bn = idx / 768;
  int n = (int)(bn % 196);
  int b = (int)(bn / 196);
  int c = f >> 8, ri = (f >> 4) & 15, cj = f & 15;
  int ph = n / 14, pw = n % 14;
  float v = x[(((long)b * 3 + c) * 224 + ph * 16 + ri) * 224 + pw * 16 + cj];
  p[idx] = f2bf(v);
}

// LayerNorm rows of h(f32)[nrows,128] -> y bf16. one wave per row.
__global__ __launch_bounds__(256) void ln_k(const float* __restrict__ h,
                                            const float* __restrict__ g,
                                            const float* __restrict__ bb,
                                            u16* __restrict__ y) {
  int row = blockIdx.x * 4 + (threadIdx.x >> 6);
  int lane = threadIdx.x & 63;
  float2 x = *(const float2*)&h[(long)row * 128 + lane * 2];
  float mu = wsum(x.x + x.y) * 0.0078125f;
  float d0 = x.x - mu, d1 = x.y - mu;
  float var = wsum(d0 * d0 + d1 * d1) * 0.0078125f;
  float rs = 1.f / sqrtf(var + 1e-5f);
  float2 gv = *(const float2*)&g[lane * 2];
  float2 bv = *(const float2*)&bb[lane * 2];
  ushort2 o;
  o.x = f2bf(d0 * rs * gv.x + bv.x);
  o.y = f2bf(d1 * rs * gv.y + bv.y);
  *(ushort2*)&y[(long)row * 128 + lane * 2] = o;
}

// row softmax over 196 local sims, writes bf16 P padded to 224 (zeros)
__global__ __launch_bounds__(256) void softmax_k(const float* __restrict__ sim,
                                                 u16* __restrict__ p) {
  int row = blockIdx.x * 4 + (threadIdx.x >> 6);
  int lane = threadIdx.x & 63;
  const float* sr = sim + (long)row * 224;
  float v[4];
#pragma unroll
  for (int t = 0; t < 4; t++) {
    int j = t * 64 + lane;
    v[t] = (j < 196) ? sr[j] : -1e30f;
  }
  float mx = wmaxr(fmaxf(fmaxf(v[0], v[1]), fmaxf(v[2], v[3])));
  float e[4], s = 0.f;
#pragma unroll
  for (int t = 0; t < 4; t++) {
    int j = t * 64 + lane;
    e[t] = (j < 196) ? expf(v[t] - mx) : 0.f;
    s += e[t];
  }
  s = wsum(s);
  float inv = 1.f / s;
  u16* pr = p + (long)row * 224;
#pragma unroll
  for (int t = 0; t < 4; t++) {
    int j = t * 64 + lane;
    if (j < 224) pr[j] = f2bf(e[t] * inv);
  }
}

// joint softmax over [32 memory scores | 196 local sims]
__global__ __launch_bounds__(256) void knn_softmax_k(
    const float* __restrict__ sim, const float* __restrict__ mvals,
    u16* __restrict__ p, float* __restrict__ am) {
  int row = blockIdx.x * 4 + (threadIdx.x >> 6);
  int lane = threadIdx.x & 63;
  const float* sr = sim + (long)row * 224;
  float v[4];
#pragma unroll
  for (int t = 0; t < 4; t++) {
    int j = t * 64 + lane;
    v[t] = (j < 196) ? sr[j] : -1e30f;
  }
  float mvv = (lane < 32) ? mvals[(long)row * 32 + lane] : -1e30f;
  float mx = wmaxr(fmaxf(fmaxf(fmaxf(v[0], v[1]), fmaxf(v[2], v[3])), mvv));
  float e[4], s = 0.f;
#pragma unroll
  for (int t = 0; t < 4; t++) {
    int j = t * 64 + lane;
    e[t] = (j < 196) ? expf(v[t] - mx) : 0.f;
    s += e[t];
  }
  float em = (lane < 32) ? expf(mvv - mx) : 0.f;
  s = wsum(s + em);
  float inv = 1.f / s;
  u16* pr = p + (long)row * 224;
#pragma unroll
  for (int t = 0; t < 4; t++) {
    int j = t * 64 + lane;
    if (j < 224) pr[j] = f2bf(e[t] * inv);
  }
  if (lane < 32) am[(long)row * 32 + lane] = em * inv;
}

// ---------------------------------------------------------------------------
// fused msim (q @ knn_k^T * SCALE) + streaming per-lane top-8 candidate lists.
// grid (8 key-splits, 2 row-splits, 32 batch). Writes 128 packed candidates
// per (row, key-split) -> cand[row][1024].
// ---------------------------------------------------------------------------
__global__ __launch_bounds__(256) void msim_topk_k(
    const u16* __restrict__ qkv, const float* __restrict__ knnk,
    unsigned* __restrict__ cand) {
  __shared__ u16 qs[112][136];
  __shared__ u16 ks[4][16][136];
  const int tid = threadIdx.x, w = tid >> 6, lane = tid & 63;
  const int b = blockIdx.z, n0 = blockIdx.y * 112, kq0 = blockIdx.x * 1024;
  const int nval = 196 - n0;
  const u16* qb = qkv + (long)b * 196 * 384;
#pragma unroll
  for (int t = 0; t < 7; t++) {
    int task = tid + t * 256;
    int r = task >> 4, k8 = (task & 15) * 8;
    short8 v = {0, 0, 0, 0, 0, 0, 0, 0};
    if (r < nval) v = *(const short8*)(qb + (long)(n0 + r) * 384 + k8);
    *(short8*)&qs[r][k8] = v;
  }
  __syncthreads();
  const int lr = lane & 15, lk = (lane >> 4) * 8;
  unsigned st[7][8], stmin[7];
#pragma unroll
  for (int s = 0; s < 7; s++) {
    stmin[s] = 0u;
#pragma unroll
    for (int t = 0; t < 8; t++) st[s][t] = 0u;
  }
  const float* kb = knnk + ((long)b * 8192 + kq0) * 128;
  const int row_l = lane >> 2, slot = lane & 3;
  const int qsel = lane >> 4, rsel = (lane >> 2) & 3;
#pragma unroll 1
  for (int c = 0; c < 16; c++) {
    int key0 = (c * 4 + w) * 16;  // wave-private 16-key chunk
    {
      int key = lane >> 2, db = (lane & 3) * 32;
      const float* src = kb + (long)(key0 + key) * 128 + db;
#pragma unroll
      for (int q4 = 0; q4 < 8; q4++) {
        float4 fv = *(const float4*)(src + q4 * 4);
        ushort4 uv;
        uv.x = f2bf(fv.x);
        uv.y = f2bf(fv.y);
        uv.z = f2bf(fv.z);
        uv.w = f2bf(fv.w);
        *(ushort4*)&ks[w][key][db + q4 * 4] = uv;
      }
    }
    __syncthreads();
    short8 bfr[4];
#pragma unroll
    for (int kc = 0; kc < 4; kc++) bfr[kc] = *(const short8*)&ks[w][lr][kc * 32 + lk];
#pragma unroll
    for (int s = 0; s < 7; s++) {
      if (n0 + s * 16 < 196) {
        floatx4 acc = {0.f, 0.f, 0.f, 0.f};
#pragma unroll
        for (int kc = 0; kc < 4; kc++) {
          short8 af = *(const short8*)&qs[s * 16 + lr][kc * 32 + lk];
          acc = __builtin_amdgcn_mfma_f32_16x16x32_bf16(af, bfr[kc], acc, 0, 0, 0);
        }
        // shfl-transpose C-layout -> (row_l, slot) lane ownership
#pragma unroll
        for (int j = 0; j < 4; j++) {
          int sl = qsel * 16 + slot * 4 + j;
          float t0 = __shfl(acc[0], sl), t1 = __shfl(acc[1], sl);
          float t2 = __shfl(acc[2], sl), t3 = __shfl(acc[3], sl);
          float v = (rsel == 0) ? t0 : (rsel == 1) ? t1 : (rsel == 2) ? t2 : t3;
          v *= ATT_SCALE;
          unsigned pk = pack_sc(v, (unsigned)(kq0 + key0 + slot * 4 + j));
          if (pk > stmin[s]) {
            unsigned mv = stmin[s];
            bool done = false;
#pragma unroll
            for (int t = 0; t < 8; t++)
              if (!done && st[s][t] == mv) {
                st[s][t] = pk;
                done = true;
              }
            unsigned nm = st[s][0];
#pragma unroll
            for (int t = 1; t < 8; t++) nm = min(nm, st[s][t]);
            stmin[s] = nm;
          }
        }
      }
    }
  }
#pragma unroll
  for (int s = 0; s < 7; s++) {
    int n = n0 + s * 16 + row_l;
    if (n < 196) {
      unsigned* dst = cand + ((long)b * 196 + n) * 1024 + blockIdx.x * 128 + w * 32 + slot * 8;
#pragma unroll
      for (int t = 0; t < 8; t++) dst[t] = st[s][t];
    }
  }
}

// merge 1024 candidates/row -> exact top-32 of the candidate set
__global__ __launch_bounds__(256) void topk_merge_k(
    const unsigned* __restrict__ cand, float* __restrict__ mvals,
    int* __restrict__ midx) {
  int row = blockIdx.x * 4 + (threadIdx.x >> 6);
  int lane = threadIdx.x & 63;
  const unsigned* cr = cand + (long)row * 1024;
  unsigned c[16];
#pragma unroll
  for (int t = 0; t < 16; t++) c[t] = cr[t * 64 + lane];
  float* mv = mvals + (long)row * 32;
  int* mi = midx + (long)row * 32;
  for (int r = 0; r < 32; r++) {
    unsigned lm = c[0];
#pragma unroll
    for (int t = 1; t < 16; t++) lm = max(lm, c[t]);
    unsigned gm = lm;
#pragma unroll
    for (int m = 32; m >= 1; m >>= 1) gm = max(gm, (unsigned)__shfl_xor((int)gm, m));
    bool has = false;
#pragma unroll
    for (int t = 0; t < 16; t++)
      if (!has && c[t] == gm) {
        c[t] = 0u;
        has = true;
      }
    if (has) {  // packed values unique (idx in low bits) -> exactly one lane
      mv[r] = unpack_sc(gm);
      mi[r] = (int)(gm & 0xFFFFu);
    }
  }
}

// o32[row][d] = sum_k am[k] * knn_v[b][midx[k]][d]
__global__ __launch_bounds__(256) void knn_gather_k(
    const float* __restrict__ am, const int* __restrict__ ix,
    const float* __restrict__ kv, float* __restrict__ o32) {
  int row = blockIdx.x * 4 + (threadIdx.x >> 6);
  int lane = threadIdx.x & 63;
  int b = row / 196;
  const float* vb = kv + (long)b * 8192 * 128;
  const float* ar = am + (long)row * 32;
  const int* xr = ix + (long)row * 32;
  float a0 = 0.f, a1 = 0.f;
#pragma unroll 4
  for (int k = 0; k < 32; k++) {
    float wv = ar[k];
    int id = xr[k];
    float2 v = *(const float2*)&vb[(long)id * 128 + lane * 2];
    a0 += wv * v.x;
    a1 += wv * v.y;
  }
  float2 o;
  o.x = a0;
  o.y = a1;
  *(float2*)&o32[(long)row * 128 + lane * 2] = o;
}

// final LN + token-mean + head GEMM. one block per batch.
__global__ __launch_bounds__(256) void final_k(
    const float* __restrict__ h, const float* __restrict__ g,
    const float* __restrict__ bb, const float* __restrict__ hw,
    const float* __restrict__ hb, float* __restrict__ out) {
  __shared__ float fw[4][128];
  __shared__ float feats[128];
  int tid = threadIdx.x, w = tid >> 6, lane = tid & 63;
  int b = blockIdx.x;
  float2 gv = *(const float2*)&g[lane * 2];
  float2 bv = *(const float2*)&bb[lane * 2];
  float a0 = 0.f, a1 = 0.f;
  for (int r = w; r < 196; r += 4) {
    float2 x = *(const float2*)&h[((long)b * 196 + r) * 128 + lane * 2];
    float mu = wsum(x.x + x.y) * 0.0078125f;
    float d0 = x.x - mu, d1 = x.y - mu;
    float var = wsum(d0 * d0 + d1 * d1) * 0.0078125f;
    float rs = 1.f / sqrtf(var + 1e-5f);
    a0 += d0 * rs * gv.x + bv.x;
    a1 += d1 * rs * gv.y + bv.y;
  }
  fw[w][lane * 2] = a0;
  fw[w][lane * 2 + 1] = a1;
  __syncthreads();
  if (tid < 128) feats[tid] = (fw[0][tid] + fw[1][tid] + fw[2][tid] + fw[3][tid]) * (1.f / 196.f);
  __syncthreads();
  for (int o = tid; o < 1000; o += 256) {
    float acc = hb[o];
    for (int d = 0; d < 128; d++) acc += feats[d] * hw[d * 1000 + o];
    out[(long)b * 1000 + o] = acc;
  }
}

// ---------------------------------------------------------------------------
extern "C" void kernel_launch(void* const* d_in, const int* in_sizes, int n_in,
                              void* d_out, int out_size, void* d_ws, size_t ws_size,
                              hipStream_t stream) {
  (void)in_sizes; (void)n_in; (void)out_size; (void)ws_size;
  const float* x       = (const float*)d_in[0];
  const float* patch_w = (const float*)d_in[1];
  const float* patch_b = (const float*)d_in[2];
  const float* ln1_g   = (const float*)d_in[3];
  const float* ln1_b   = (const float*)d_in[4];
  const float* qkv_w   = (const float*)d_in[5];
  const float* qkv_b   = (const float*)d_in[6];
  const float* out_w   = (const float*)d_in[7];
  const float* out_b   = (const float*)d_in[8];
  const float* ln2_g   = (const float*)d_in[9];
  const float* ln2_b   = (const float*)d_in[10];
  const float* ff1_w   = (const float*)d_in[11];
  const float* ff1_b   = (const float*)d_in[12];
  const float* ff2_w   = (const float*)d_in[13];
  const float* ff2_b   = (const float*)d_in[14];
  const float* lnf_g   = (const float*)d_in[15];
  const float* lnf_b   = (const float*)d_in[16];
  const float* knn_k   = (const float*)d_in[17];
  const float* knn_v   = (const float*)d_in[18];
  const float* head_w  = (const float*)d_in[19];
  const float* head_b  = (const float*)d_in[20];

  char* ws = (char*)d_ws;
  size_t off = 0;
  u16* wbf = (u16*)(ws + off);        off += 2949120;   // transposed bf16 weights
  u16* p_bf = (u16*)(ws + off);       off += 9633792;   // 6272x768 bf16
  float* h = (float*)(ws + off);      off += 3211264;   // 6272x128 f32 residual
  u16* y_bf = (u16*)(ws + off);       off += 1605632;   // 6272x128 bf16
  u16* qkvb = (u16*)(ws + off);       off += 4816896;   // 6272x384 bf16
  u16* g_bf = (u16*)(ws + off);       off += 6422528;   // 6272x512 bf16
  u16* o_bf = (u16*)(ws + off);       off += 1605632;   // 6272x128 bf16
  float* o32 = (float*)(ws + off);    off += 3211264;   // 6272x128 f32
  float* simf = (float*)(ws + off);   off += 5619712;   // 32x196x224 f32
  u16* pbf = (u16*)(ws + off);        off += 2809856;   // 32x196x224 bf16
  unsigned* cand = (unsigned*)(ws + off); off += 25690112; // 6272x1024 u32
  float* mvals = (float*)(ws + off);  off += 802816;    // 6272x32
  int* midx = (int*)(ws + off);       off += 802816;
  float* amf = (float*)(ws + off);    off += 802816;

  dim3 blk(256);
  cvtw_k<<<5760, blk, 0, stream>>>(patch_w, qkv_w, out_w, ff1_w, ff2_w, wbf);
  patchify_k<<<18816, blk, 0, stream>>>(x, p_bf);
  // h = p @ patch_w + patch_b
  gemm_k<0, false><<<dim3(49, 2, 1), blk, 0, stream>>>(
      p_bf, 768, 0, wbf, 768, 0, 768, patch_b, nullptr, 0, h, 128, 0, 6272, 128, 768, 1.f);

  for (int i = 0; i < 7; i++) {
    ln_k<<<1568, blk, 0, stream>>>(h, ln1_g + i * 128, ln1_b + i * 128, y_bf);
    gemm_k<1, false><<<dim3(49, 6, 1), blk, 0, stream>>>(
        y_bf, 128, 0, wbf + 98304 + i * 49152, 128, 0, 128, qkv_b + i * 384,
        nullptr, 0, qkvb, 384, 0, 6272, 384, 128, 1.f);
    if (i == 6) {
      msim_topk_k<<<dim3(8, 2, 32), blk, 0, stream>>>(qkvb, knn_k, cand);
      topk_merge_k<<<1568, blk, 0, stream>>>(cand, mvals, midx);
    }
    // local sims: S = q @ k^T * SCALE (batched)
    gemm_k<4, false><<<dim3(2, 4, 32), blk, 0, stream>>>(
        qkvb, 384, (long)196 * 384, qkvb + 128, 384, (long)196 * 384, 128,
        nullptr, nullptr, 0, simf, 224, (long)196 * 224, 196, 196, 128, ATT_SCALE);
    if (i == 6) {
      knn_softmax_k<<<1568, blk, 0, stream>>>(simf, mvals, pbf, amf);
      knn_gather_k<<<1568, blk, 0, stream>>>(amf, midx, knn_v, o32);
      gemm_k<5, true><<<dim3(2, 2, 32), blk, 0, stream>>>(
          pbf, 224, (long)196 * 224, qkvb + 256, 384, (long)196 * 384, 196,
          nullptr, o32, (long)196 * 128, o_bf, 128, (long)196 * 128, 196, 128, 224, 1.f);
    } else {
      softmax_k<<<1568, blk, 0, stream>>>(simf, pbf);
      gemm_k<5, true><<<dim3(2, 2, 32), blk, 0, stream>>>(
          pbf, 224, (long)196 * 224, qkvb + 256, 384, (long)196 * 384, 196,
          nullptr, nullptr, 0, o_bf, 128, (long)196 * 128, 196, 128, 224, 1.f);
    }
    // h += o @ out_w + out_b
    gemm_k<3, false><<<dim3(49, 2, 1), blk, 0, stream>>>(
        o_bf, 128, 0, wbf + 442368 + i * 16384, 128, 0, 128, out_b + i * 128,
        h, 0, h, 128, 0, 6272, 128, 128, 1.f);
    ln_k<<<1568, blk, 0, stream>>>(h, ln2_g + i * 128, ln2_b + i * 128, y_bf);
    gemm_k<2, false><<<dim3(49, 8, 1), blk, 0, stream>>>(
        y_bf, 128, 0, wbf + 557056 + i * 65536, 128, 0, 128, ff1_b + i * 512,
        nullptr, 0, g_bf, 512, 0, 6272, 512, 128, 1.f);
    gemm_k<3, false><<<dim3(49, 2, 1), blk, 0, stream>>>(
        g_bf, 512, 0, wbf + 1015808 + i * 65536, 512, 0, 512, ff2_b + i * 128,
        h, 0, h, 128, 0, 6272, 128, 512, 1.f);
  }
  final_k<<<32, blk, 0, stream>>>(h, lnf_g, lnf_b, head_w, head_b, (float*)d_out);
}

// Round 2
// 1237.658 us; speedup vs baseline: 1.0388x; 1.0388x over previous
//
#include <hip/hip_runtime.h>
#include <hip/hip_fp16.h>

typedef unsigned short u16;
typedef __attribute__((ext_vector_type(8))) short short8;
typedef __attribute__((ext_vector_type(4))) float floatx4;

#define ATT_SCALE 0.08838834764831845f

__device__ __forceinline__ u16 f2bf(float f) {
  unsigned u = __float_as_uint(f);
  u += 0x7FFFu + ((u >> 16) & 1u);
  return (u16)(u >> 16);
}

// round-to-nearest bf16 of a,b packed into one u32 (low16=bf(a))
__device__ __forceinline__ unsigned bfpack(float a, float b) {
  unsigned ua = __float_as_uint(a);
  ua += 0x7FFFu + ((ua >> 16) & 1u);
  unsigned ub = __float_as_uint(b);
  ub += 0x7FFFu + ((ub >> 16) & 1u);
  return __builtin_amdgcn_perm(ub, ua, 0x07060302u);
}

__device__ __forceinline__ float wsum(float v) {
#pragma unroll
  for (int m = 32; m >= 1; m >>= 1) v += __shfl_xor(v, m);
  return v;
}
__device__ __forceinline__ float wmaxr(float v) {
#pragma unroll
  for (int m = 32; m >= 1; m >>= 1) v = fmaxf(v, __shfl_xor(v, m));
  return v;
}

// packed candidate: monotone-f32 bits [31:13] | key idx (13 bits)
__device__ __forceinline__ float unpack_sc(unsigned p) {
  unsigned mono = p & 0xFFFFE000u;
  unsigned ub = (mono & 0x80000000u) ? (mono ^ 0x80000000u) : ~mono;
  return __uint_as_float(ub);
}

// ---------------------------------------------------------------------------
// Generic bf16 MFMA GEMM: C[M,N] = epilogue(A[M,K] @ B^T[N,K] + bias)
// A row-major (lda), B stored [n][k] (ldb) unless BT: B raw [k][n] (ldb), k<Kb.
// EPI: 0 f32 alpha*acc+bias | 1 bf16 acc+bias | 2 bf16 gelu(acc+bias)
//      3 f32 add+acc+bias (residual) | 4 f32 alpha*acc | 5 bf16 acc+add(optional)
// ---------------------------------------------------------------------------
template <int EPI, bool BT>
__global__ __launch_bounds__(256) void gemm_k(
    const u16* __restrict__ A, int lda, long sA,
    const u16* __restrict__ B, int ldb, long sB, int Kb,
    const float* __restrict__ bias,
    const float* __restrict__ add, long sAdd,
    void* __restrict__ Cv, int ldc, long sC,
    int M, int N, int K, float alpha) {
  __shared__ u16 As[128][40];  // +8 pad: conflict-free b128 frag reads
  __shared__ u16 Bs[64][40];
  const int tid = threadIdx.x;
  const int m0 = blockIdx.x * 128, n0 = blockIdx.y * 64;
  const int bz = blockIdx.z;
  A += (long)bz * sA;
  B += (long)bz * sB;
  const int w = tid >> 6, lane = tid & 63;
  const int wr = w & 1, wc = w >> 1;
  const int lr = lane & 15, lk = (lane >> 4) * 8;
  floatx4 zf = {0.f, 0.f, 0.f, 0.f};
  floatx4 acc[4][2];
#pragma unroll
  for (int i = 0; i < 4; i++)
#pragma unroll
    for (int j = 0; j < 2; j++) acc[i][j] = zf;

  for (int k0 = 0; k0 < K; k0 += 32) {
#pragma unroll
    for (int t = 0; t < 2; t++) {
      int task = tid + t * 256;
      int r = task >> 2, k8 = (task & 3) * 8;
      short8 v = {0, 0, 0, 0, 0, 0, 0, 0};
      if (m0 + r < M) v = *(const short8*)(A + (long)(m0 + r) * lda + k0 + k8);
      *(short8*)&As[r][k8] = v;
    }
    if (!BT) {
      int r = tid >> 2, k8 = (tid & 3) * 8;
      short8 v = {0, 0, 0, 0, 0, 0, 0, 0};
      if (n0 + r < N) v = *(const short8*)(B + (long)(n0 + r) * ldb + k0 + k8);
      *(short8*)&Bs[r][k8] = v;
    } else {
#pragma unroll
      for (int t = 0; t < 8; t++) {
        int task = tid + t * 256;
        int n = task & 63, kk = task >> 6;
        u16 v = 0;
        if (k0 + kk < Kb && n0 + n < N) v = B[(long)(k0 + kk) * ldb + n0 + n];
        Bs[n][kk] = v;
      }
    }
    __syncthreads();
    short8 af[4], bfr[2];
#pragma unroll
    for (int i = 0; i < 4; i++) af[i] = *(const short8*)&As[wr * 64 + i * 16 + lr][lk];
#pragma unroll
    for (int j = 0; j < 2; j++) bfr[j] = *(const short8*)&Bs[wc * 32 + j * 16 + lr][lk];
#pragma unroll
    for (int i = 0; i < 4; i++)
#pragma unroll
      for (int j = 0; j < 2; j++)
        acc[i][j] = __builtin_amdgcn_mfma_f32_16x16x32_bf16(af[i], bfr[j], acc[i][j], 0, 0, 0);
    __syncthreads();
  }
#pragma unroll
  for (int i = 0; i < 4; i++) {
#pragma unroll
    for (int j = 0; j < 2; j++) {
      int gn = n0 + wc * 32 + j * 16 + lr;
#pragma unroll
      for (int r = 0; r < 4; r++) {
        int gm = m0 + wr * 64 + i * 16 + (lane >> 4) * 4 + r;
        if (gm < M && gn < N) {
          float v = acc[i][j][r];
          float bi = bias ? bias[gn] : 0.f;
          long co = (long)bz * sC + (long)gm * ldc + gn;
          if (EPI == 0) {
            ((float*)Cv)[co] = v * alpha + bi;
          } else if (EPI == 1) {
            ((u16*)Cv)[co] = f2bf(v + bi);
          } else if (EPI == 2) {
            float t = v + bi;
            float g = 0.5f * t * (1.f + tanhf(0.7978845608028654f * (t + 0.044715f * t * t * t)));
            ((u16*)Cv)[co] = f2bf(g);
          } else if (EPI == 3) {
            ((float*)Cv)[co] = add[(long)gm * ldc + gn] + v + bi;
          } else if (EPI == 4) {
            ((float*)Cv)[co] = v * alpha;
          } else {
            float t = v + (add ? add[(long)bz * sAdd + (long)gm * ldc + gn] : 0.f);
            ((u16*)Cv)[co] = f2bf(t);
          }
        }
      }
    }
  }
}

// ---------------------------------------------------------------------------
// Fused LayerNorm + GEMM for K = D = 128 (single staging phase, no k-loop).
// C[M=6272, N] = epi(LN(H) @ B^T + bias).  EPI: 1 bf16 | 2 bf16 gelu
// ---------------------------------------------------------------------------
template <int EPI>
__global__ __launch_bounds__(256) void lngemm_k(
    const float* __restrict__ H, const float* __restrict__ g,
    const float* __restrict__ bb, const u16* __restrict__ B,
    const float* __restrict__ bias, u16* __restrict__ C, int ldc, int N) {
  __shared__ u16 As[128][136];
  __shared__ u16 Bs[64][136];
  __shared__ float stats[128][4];
  const int tid = threadIdx.x;
  const int m0 = blockIdx.x * 128, n0 = blockIdx.y * 64;
  // stage B tile 64xN
#pragma unroll
  for (int t = 0; t < 4; t++) {
    int task = tid + t * 256;
    int rb = task >> 4, c8 = (task & 15) * 8;
    short8 v = *(const short8*)(B + (long)(n0 + rb) * 128 + c8);
    *(short8*)&Bs[rb][c8] = v;
  }
  // LN staging of A: 2 threads per row
  const int row = tid >> 1, half = tid & 1;
  float4 xv[16];
  const float* hp = H + (long)(m0 + row) * 128 + half * 64;
  float s1 = 0.f, s2 = 0.f;
#pragma unroll
  for (int t = 0; t < 16; t++) {
    xv[t] = *(const float4*)(hp + t * 4);
    s1 += xv[t].x + xv[t].y + xv[t].z + xv[t].w;
    s2 += xv[t].x * xv[t].x + xv[t].y * xv[t].y + xv[t].z * xv[t].z + xv[t].w * xv[t].w;
  }
  stats[row][half * 2] = s1;
  stats[row][half * 2 + 1] = s2;
  __syncthreads();
  float fs1 = stats[row][0] + stats[row][2];
  float fs2 = stats[row][1] + stats[row][3];
  float mu = fs1 * 0.0078125f;
  float var = fs2 * 0.0078125f - mu * mu;
  float rs = rsqrtf(var + 1e-5f);
  const float* gp = g + half * 64;
  const float* bp = bb + half * 64;
#pragma unroll
  for (int t = 0; t < 16; t++) {
    float4 gv = *(const float4*)(gp + t * 4);
    float4 bv = *(const float4*)(bp + t * 4);
    ushort4 o;
    o.x = f2bf((xv[t].x - mu) * rs * gv.x + bv.x);
    o.y = f2bf((xv[t].y - mu) * rs * gv.y + bv.y);
    o.z = f2bf((xv[t].z - mu) * rs * gv.z + bv.z);
    o.w = f2bf((xv[t].w - mu) * rs * gv.w + bv.w);
    *(ushort4*)&As[row][half * 64 + t * 4] = o;
  }
  __syncthreads();
  const int w = tid >> 6, lane = tid & 63;
  const int wr = w & 1, wc = w >> 1;
  const int lr = lane & 15, lk = (lane >> 4) * 8;
  floatx4 zf = {0.f, 0.f, 0.f, 0.f};
  floatx4 acc[4][2];
#pragma unroll
  for (int i = 0; i < 4; i++)
#pragma unroll
    for (int j = 0; j < 2; j++) acc[i][j] = zf;
#pragma unroll
  for (int kc = 0; kc < 4; kc++) {
    short8 afr[4], bfr[2];
#pragma unroll
    for (int i = 0; i < 4; i++) afr[i] = *(const short8*)&As[wr * 64 + i * 16 + lr][kc * 32 + lk];
#pragma unroll
    for (int j = 0; j < 2; j++) bfr[j] = *(const short8*)&Bs[wc * 32 + j * 16 + lr][kc * 32 + lk];
#pragma unroll
    for (int i = 0; i < 4; i++)
#pragma unroll
      for (int j = 0; j < 2; j++)
        acc[i][j] = __builtin_amdgcn_mfma_f32_16x16x32_bf16(afr[i], bfr[j], acc[i][j], 0, 0, 0);
  }
#pragma unroll
  for (int i = 0; i < 4; i++) {
#pragma unroll
    for (int j = 0; j < 2; j++) {
      int gn = n0 + wc * 32 + j * 16 + lr;
#pragma unroll
      for (int r = 0; r < 4; r++) {
        int gm = m0 + wr * 64 + i * 16 + (lane >> 4) * 4 + r;
        float v = acc[i][j][r] + bias[gn];
        if (EPI == 2) {
          v = 0.5f * v * (1.f + tanhf(0.7978845608028654f * (v + 0.044715f * v * v * v)));
        }
        C[(long)gm * ldc + gn] = f2bf(v);
      }
    }
  }
}

// ---------------------------------------------------------------------------
// weight convert + transpose to bf16 [n][k] layouts
// ---------------------------------------------------------------------------
__global__ __launch_bounds__(256) void cvtw_k(
    const float* __restrict__ pw, const float* __restrict__ qw,
    const float* __restrict__ ow, const float* __restrict__ f1,
    const float* __restrict__ f2, u16* __restrict__ wbf) {
  int idx = blockIdx.x * 256 + threadIdx.x;
  float v;
  if (idx < 98304) {
    int n = idx / 768, k = idx % 768;
    v = pw[k * 128 + n];
  } else if (idx < 442368) {
    int rel = idx - 98304;
    int i = rel / 49152, r = rel % 49152, n = r / 128, k = r % 128;
    v = qw[((long)i * 128 + k) * 384 + n];
  } else if (idx < 557056) {
    int rel = idx - 442368;
    int i = rel / 16384, r = rel % 16384, n = r / 128, k = r % 128;
    v = ow[((long)i * 128 + k) * 128 + n];
  } else if (idx < 1015808) {
    int rel = idx - 557056;
    int i = rel / 65536, r = rel % 65536, n = r / 128, k = r % 128;
    v = f1[((long)i * 128 + k) * 512 + n];
  } else {
    int rel = idx - 1015808;
    int i = rel / 65536, r = rel % 65536, n = r / 512, k = r % 512;
    v = f2[((long)i * 512 + k) * 128 + n];
  }
  wbf[idx] = f2bf(v);
}

// patchify x(32,3,224,224) -> p_bf(32,196,768) bf16
__global__ __launch_bounds__(256) void patchify_k(const float* __restrict__ x,
                                                  u16* __restrict__ p) {
  long idx = (long)blockIdx.x * 256 + threadIdx.x;
  int f = (int)(idx % 768);
  long bn = idx / 768;
  int n = (int)(bn % 196);
  int b = (int)(bn / 196);
  int c = f >> 8, ri = (f >> 4) & 15, cj = f & 15;
  int ph = n / 14, pw = n % 14;
  float v = x[(((long)b * 3 + c) * 224 + ph * 16 + ri) * 224 + pw * 16 + cj];
  p[idx] = f2bf(v);
}

// row softmax over 196 local sims, writes bf16 P padded to 224 (zeros)
__global__ __launch_bounds__(256) void softmax_k(const float* __restrict__ sim,
                                                 u16* __restrict__ p) {
  int row = blockIdx.x * 4 + (threadIdx.x >> 6);
  int lane = threadIdx.x & 63;
  const float* sr = sim + (long)row * 224;
  float v[4];
#pragma unroll
  for (int t = 0; t < 4; t++) {
    int j = t * 64 + lane;
    v[t] = (j < 196) ? sr[j] : -1e30f;
  }
  float mx = wmaxr(fmaxf(fmaxf(v[0], v[1]), fmaxf(v[2], v[3])));
  float e[4], s = 0.f;
#pragma unroll
  for (int t = 0; t < 4; t++) {
    int j = t * 64 + lane;
    e[t] = (j < 196) ? expf(v[t] - mx) : 0.f;
    s += e[t];
  }
  s = wsum(s);
  float inv = 1.f / s;
  u16* pr = p + (long)row * 224;
#pragma unroll
  for (int t = 0; t < 4; t++) {
    int j = t * 64 + lane;
    if (j < 224) pr[j] = f2bf(e[t] * inv);
  }
}

// joint softmax over [32 memory scores | 196 local sims]
__global__ __launch_bounds__(256) void knn_softmax_k(
    const float* __restrict__ sim, const float* __restrict__ mvals,
    u16* __restrict__ p, float* __restrict__ am) {
  int row = blockIdx.x * 4 + (threadIdx.x >> 6);
  int lane = threadIdx.x & 63;
  const float* sr = sim + (long)row * 224;
  float v[4];
#pragma unroll
  for (int t = 0; t < 4; t++) {
    int j = t * 64 + lane;
    v[t] = (j < 196) ? sr[j] : -1e30f;
  }
  float mvv = (lane < 32) ? mvals[(long)row * 32 + lane] : -1e30f;
  float mx = wmaxr(fmaxf(fmaxf(fmaxf(v[0], v[1]), fmaxf(v[2], v[3])), mvv));
  float e[4], s = 0.f;
#pragma unroll
  for (int t = 0; t < 4; t++) {
    int j = t * 64 + lane;
    e[t] = (j < 196) ? expf(v[t] - mx) : 0.f;
    s += e[t];
  }
  float em = (lane < 32) ? expf(mvv - mx) : 0.f;
  s = wsum(s + em);
  float inv = 1.f / s;
  u16* pr = p + (long)row * 224;
#pragma unroll
  for (int t = 0; t < 4; t++) {
    int j = t * 64 + lane;
    if (j < 224) pr[j] = f2bf(e[t] * inv);
  }
  if (lane < 32) am[(long)row * 32 + lane] = em * inv;
}

// ---------------------------------------------------------------------------
// msim + streaming top-k, v2: keys loaded straight into MFMA B-fragment
// layout (no LDS staging, no hot-loop barriers), q frags preloaded in regs,
// C->row transpose via per-wave double-buffered LDS scratch, branchless
// sorted top-8 insert on packed (mono-f32[31:13] | idx13) keys.
// grid (8 key-splits, 4 row-splits of 49, 32 batch).
// ---------------------------------------------------------------------------
__global__ __launch_bounds__(256) void msim_topk_k(
    const u16* __restrict__ qkv, const float* __restrict__ knnk,
    unsigned* __restrict__ cand) {
  __shared__ u16 qs[64][136];
  __shared__ float scr[4][2][320];
  const int tid = threadIdx.x, w = tid >> 6, lane = tid & 63;
  const int b = blockIdx.z, n0 = blockIdx.y * 49, kq0 = blockIdx.x * 1024;
  const u16* qb = qkv + (long)b * 196 * 384;
#pragma unroll
  for (int t = 0; t < 4; t++) {
    int task = tid + t * 256;
    int r = task >> 4, c8 = (task & 15) * 8;
    short8 v = {0, 0, 0, 0, 0, 0, 0, 0};
    if (r < 49) v = *(const short8*)(qb + (long)(n0 + r) * 384 + c8);
    *(short8*)&qs[r][c8] = v;
  }
  __syncthreads();
  const int lr = lane & 15, lq = lane >> 4, lk = lq * 8;
  short8 af[4][4];
#pragma unroll
  for (int s = 0; s < 4; s++)
#pragma unroll
    for (int kc = 0; kc < 4; kc++)
      af[s][kc] = *(const short8*)&qs[s * 16 + lr][kc * 32 + lk];

  unsigned st[4][8];
#pragma unroll
  for (int s = 0; s < 4; s++)
#pragma unroll
    for (int t = 0; t < 8; t++) st[s][t] = 0u;

  const float* kbase = knnk + ((long)b * 8192 + kq0 + lr) * 128 + lk;
  const int idx0 = kq0 + lq * 4;

#pragma unroll 1
  for (int c = 0; c < 16; c++) {
    const int key0 = (c * 4 + w) * 16;
    const float* kp = kbase + (long)key0 * 128;
    short8 bfr[4];
#pragma unroll
    for (int kc = 0; kc < 4; kc++) {
      float4 x0 = *(const float4*)(kp + kc * 32);
      float4 x1 = *(const float4*)(kp + kc * 32 + 4);
      int4 iv;
      iv.x = (int)bfpack(x0.x, x0.y);
      iv.y = (int)bfpack(x0.z, x0.w);
      iv.z = (int)bfpack(x1.x, x1.y);
      iv.w = (int)bfpack(x1.z, x1.w);
      bfr[kc] = *(short8*)&iv;
    }
    const int ib = idx0 + key0;
#pragma unroll
    for (int s = 0; s < 4; s++) {
      floatx4 acc = {0.f, 0.f, 0.f, 0.f};
#pragma unroll
      for (int kc = 0; kc < 4; kc++)
        acc = __builtin_amdgcn_mfma_f32_16x16x32_bf16(af[s][kc], bfr[kc], acc, 0, 0, 0);
      float* sc = scr[w][s & 1];
      // C layout: col(key)=lr, rows lq*4+r  ->  sc[col*20 + row]
      *(floatx4*)&sc[lr * 20 + lq * 4] = acc;
#pragma unroll
      for (int j = 0; j < 4; j++) {
        float v = sc[(lq * 4 + j) * 20 + lr] * ATT_SCALE;
        unsigned u = __float_as_uint(v);
        unsigned mono = u ^ ((unsigned)((int)u >> 31) | 0x80000000u);
        unsigned x = (mono & 0xFFFFE000u) | (unsigned)(ib + j);
#pragma unroll
        for (int t = 0; t < 8; t++) {
          unsigned mx = max(st[s][t], x);
          x = min(st[s][t], x);
          st[s][t] = mx;
        }
      }
    }
  }
#pragma unroll
  for (int s = 0; s < 4; s++) {
    int rloc = s * 16 + lr;
    if (rloc < 49) {
      unsigned* dst = cand + ((long)b * 196 + n0 + rloc) * 1024 + blockIdx.x * 128 + w * 32 + lq * 8;
#pragma unroll
      for (int t = 0; t < 8; t++) dst[t] = st[s][t];
    }
  }
}

// merge 1024 candidates/row -> exact top-32 of the candidate set
__global__ __launch_bounds__(256) void topk_merge_k(
    const unsigned* __restrict__ cand, float* __restrict__ mvals,
    int* __restrict__ midx) {
  int row = blockIdx.x * 4 + (threadIdx.x >> 6);
  int lane = threadIdx.x & 63;
  const unsigned* cr = cand + (long)row * 1024;
  unsigned c[16];
#pragma unroll
  for (int t = 0; t < 16; t++) c[t] = cr[t * 64 + lane];
  float* mv = mvals + (long)row * 32;
  int* mi = midx + (long)row * 32;
  for (int r = 0; r < 32; r++) {
    unsigned lm = c[0];
#pragma unroll
    for (int t = 1; t < 16; t++) lm = max(lm, c[t]);
    unsigned gm = lm;
#pragma unroll
    for (int m = 32; m >= 1; m >>= 1) gm = max(gm, (unsigned)__shfl_xor((int)gm, m));
    bool has = false;
#pragma unroll
    for (int t = 0; t < 16; t++)
      if (!has && c[t] == gm) {
        c[t] = 0u;
        has = true;
      }
    if (has) {  // packed values unique (idx in low bits) -> exactly one lane
      mv[r] = unpack_sc(gm);
      mi[r] = (int)(gm & 0x1FFFu);
    }
  }
}

// o32[row][d] = sum_k am[k] * knn_v[b][midx[k]][d]
__global__ __launch_bounds__(256) void knn_gather_k(
    const float* __restrict__ am, const int* __restrict__ ix,
    const float* __restrict__ kv, float* __restrict__ o32) {
  int row = blockIdx.x * 4 + (threadIdx.x >> 6);
  int lane = threadIdx.x & 63;
  int b = row / 196;
  const float* vb = kv + (long)b * 8192 * 128;
  const float* ar = am + (long)row * 32;
  const int* xr = ix + (long)row * 32;
  float a0 = 0.f, a1 = 0.f;
#pragma unroll 4
  for (int k = 0; k < 32; k++) {
    float wv = ar[k];
    int id = xr[k];
    float2 v = *(const float2*)&vb[(long)id * 128 + lane * 2];
    a0 += wv * v.x;
    a1 += wv * v.y;
  }
  float2 o;
  o.x = a0;
  o.y = a1;
  *(float2*)&o32[(long)row * 128 + lane * 2] = o;
}

// final LN + token-mean + head GEMM. one block per batch.
__global__ __launch_bounds__(256) void final_k(
    const float* __restrict__ h, const float* __restrict__ g,
    const float* __restrict__ bb, const float* __restrict__ hw,
    const float* __restrict__ hb, float* __restrict__ out) {
  __shared__ float fw[4][128];
  __shared__ float feats[128];
  int tid = threadIdx.x, w = tid >> 6, lane = tid & 63;
  int b = blockIdx.x;
  float2 gv = *(const float2*)&g[lane * 2];
  float2 bv = *(const float2*)&bb[lane * 2];
  float a0 = 0.f, a1 = 0.f;
  for (int r = w; r < 196; r += 4) {
    float2 x = *(const float2*)&h[((long)b * 196 + r) * 128 + lane * 2];
    float mu = wsum(x.x + x.y) * 0.0078125f;
    float d0 = x.x - mu, d1 = x.y - mu;
    float var = wsum(d0 * d0 + d1 * d1) * 0.0078125f;
    float rs = 1.f / sqrtf(var + 1e-5f);
    a0 += d0 * rs * gv.x + bv.x;
    a1 += d1 * rs * gv.y + bv.y;
  }
  fw[w][lane * 2] = a0;
  fw[w][lane * 2 + 1] = a1;
  __syncthreads();
  if (tid < 128) feats[tid] = (fw[0][tid] + fw[1][tid] + fw[2][tid] + fw[3][tid]) * (1.f / 196.f);
  __syncthreads();
  for (int o = tid; o < 1000; o += 256) {
    float acc = hb[o];
    for (int d = 0; d < 128; d++) acc += feats[d] * hw[d * 1000 + o];
    out[(long)b * 1000 + o] = acc;
  }
}

// ---------------------------------------------------------------------------
extern "C" void kernel_launch(void* const* d_in, const int* in_sizes, int n_in,
                              void* d_out, int out_size, void* d_ws, size_t ws_size,
                              hipStream_t stream) {
  (void)in_sizes; (void)n_in; (void)out_size; (void)ws_size;
  const float* x       = (const float*)d_in[0];
  const float* patch_w = (const float*)d_in[1];
  const float* patch_b = (const float*)d_in[2];
  const float* ln1_g   = (const float*)d_in[3];
  const float* ln1_b   = (const float*)d_in[4];
  const float* qkv_w   = (const float*)d_in[5];
  const float* qkv_b   = (const float*)d_in[6];
  const float* out_w   = (const float*)d_in[7];
  const float* out_b   = (const float*)d_in[8];
  const float* ln2_g   = (const float*)d_in[9];
  const float* ln2_b   = (const float*)d_in[10];
  const float* ff1_w   = (const float*)d_in[11];
  const float* ff1_b   = (const float*)d_in[12];
  const float* ff2_w   = (const float*)d_in[13];
  const float* ff2_b   = (const float*)d_in[14];
  const float* lnf_g   = (const float*)d_in[15];
  const float* lnf_b   = (const float*)d_in[16];
  const float* knn_k   = (const float*)d_in[17];
  const float* knn_v   = (const float*)d_in[18];
  const float* head_w  = (const float*)d_in[19];
  const float* head_b  = (const float*)d_in[20];

  char* ws = (char*)d_ws;
  size_t off = 0;
  u16* wbf = (u16*)(ws + off);        off += 2949120;   // transposed bf16 weights
  u16* p_bf = (u16*)(ws + off);       off += 9633792;   // 6272x768 bf16
  float* h = (float*)(ws + off);      off += 3211264;   // 6272x128 f32 residual
  u16* qkvb = (u16*)(ws + off);       off += 4816896;   // 6272x384 bf16
  u16* g_bf = (u16*)(ws + off);       off += 6422528;   // 6272x512 bf16
  u16* o_bf = (u16*)(ws + off);       off += 1605632;   // 6272x128 bf16
  float* o32 = (float*)(ws + off);    off += 3211264;   // 6272x128 f32
  float* simf = (float*)(ws + off);   off += 5619712;   // 32x196x224 f32
  u16* pbf = (u16*)(ws + off);        off += 2809856;   // 32x196x224 bf16
  unsigned* cand = (unsigned*)(ws + off); off += 25690112; // 6272x1024 u32
  float* mvals = (float*)(ws + off);  off += 802816;    // 6272x32
  int* midx = (int*)(ws + off);       off += 802816;
  float* amf = (float*)(ws + off);    off += 802816;

  dim3 blk(256);
  cvtw_k<<<5760, blk, 0, stream>>>(patch_w, qkv_w, out_w, ff1_w, ff2_w, wbf);
  patchify_k<<<18816, blk, 0, stream>>>(x, p_bf);
  // h = p @ patch_w + patch_b
  gemm_k<0, false><<<dim3(49, 2, 1), blk, 0, stream>>>(
      p_bf, 768, 0, wbf, 768, 0, 768, patch_b, nullptr, 0, h, 128, 0, 6272, 128, 768, 1.f);

  for (int i = 0; i < 7; i++) {
    // qkv = LN1(h) @ qkv_w + qkv_b   (fused)
    lngemm_k<1><<<dim3(49, 6), blk, 0, stream>>>(
        h, ln1_g + i * 128, ln1_b + i * 128, wbf + 98304 + i * 49152,
        qkv_b + i * 384, qkvb, 384, 384);
    if (i == 6) {
      msim_topk_k<<<dim3(8, 4, 32), blk, 0, stream>>>(qkvb, knn_k, cand);
      topk_merge_k<<<1568, blk, 0, stream>>>(cand, mvals, midx);
    }
    // local sims: S = q @ k^T * SCALE (batched)
    gemm_k<4, false><<<dim3(2, 4, 32), blk, 0, stream>>>(
        qkvb, 384, (long)196 * 384, qkvb + 128, 384, (long)196 * 384, 128,
        nullptr, nullptr, 0, simf, 224, (long)196 * 224, 196, 196, 128, ATT_SCALE);
    if (i == 6) {
      knn_softmax_k<<<1568, blk, 0, stream>>>(simf, mvals, pbf, amf);
      knn_gather_k<<<1568, blk, 0, stream>>>(amf, midx, knn_v, o32);
      gemm_k<5, true><<<dim3(2, 2, 32), blk, 0, stream>>>(
          pbf, 224, (long)196 * 224, qkvb + 256, 384, (long)196 * 384, 196,
          nullptr, o32, (long)196 * 128, o_bf, 128, (long)196 * 128, 196, 128, 224, 1.f);
    } else {
      softmax_k<<<1568, blk, 0, stream>>>(simf, pbf);
      gemm_k<5, true><<<dim3(2, 2, 32), blk, 0, stream>>>(
          pbf, 224, (long)196 * 224, qkvb + 256, 384, (long)196 * 384, 196,
          nullptr, nullptr, 0, o_bf, 128, (long)196 * 128, 196, 128, 224, 1.f);
    }
    // h += o @ out_w + out_b
    gemm_k<3, false><<<dim3(49, 2, 1), blk, 0, stream>>>(
        o_bf, 128, 0, wbf + 442368 + i * 16384, 128, 0, 128, out_b + i * 128,
        h, 0, h, 128, 0, 6272, 128, 128, 1.f);
    // g = gelu(LN2(h) @ ff1_w + ff1_b)   (fused)
    lngemm_k<2><<<dim3(49, 8), blk, 0, stream>>>(
        h, ln2_g + i * 128, ln2_b + i * 128, wbf + 557056 + i * 65536,
        ff1_b + i * 512, g_bf, 512, 512);
    gemm_k<3, false><<<dim3(49, 2, 1), blk, 0, stream>>>(
        g_bf, 512, 0, wbf + 1015808 + i * 65536, 512, 0, 512, ff2_b + i * 128,
        h, 0, h, 128, 0, 6272, 128, 512, 1.f);
  }
  final_k<<<32, blk, 0, stream>>>(h, lnf_g, lnf_b, head_w, head_b, (float*)d_out);
}

// Round 3
// 1058.800 us; speedup vs baseline: 1.2143x; 1.1689x over previous
//
#include <hip/hip_runtime.h>
#include <hip/hip_fp16.h>

typedef unsigned short u16;
typedef __attribute__((ext_vector_type(8))) short short8;
typedef __attribute__((ext_vector_type(4))) float floatx4;

#define ATT_SCALE 0.08838834764831845f

__device__ __forceinline__ u16 f2bf(float f) {
  unsigned u = __float_as_uint(f);
  u += 0x7FFFu + ((u >> 16) & 1u);
  return (u16)(u >> 16);
}

// round-to-nearest bf16 of a,b packed into one u32 (low16=bf(a))
__device__ __forceinline__ unsigned bfpack(float a, float b) {
  unsigned ua = __float_as_uint(a);
  ua += 0x7FFFu + ((ua >> 16) & 1u);
  unsigned ub = __float_as_uint(b);
  ub += 0x7FFFu + ((ub >> 16) & 1u);
  return __builtin_amdgcn_perm(ub, ua, 0x07060302u);
}

__device__ __forceinline__ float wsum(float v) {
#pragma unroll
  for (int m = 32; m >= 1; m >>= 1) v += __shfl_xor(v, m);
  return v;
}
__device__ __forceinline__ float wmaxr(float v) {
#pragma unroll
  for (int m = 32; m >= 1; m >>= 1) v = fmaxf(v, __shfl_xor(v, m));
  return v;
}

// packed candidate: monotone-f32 bits [31:13] | key idx (13 bits)
__device__ __forceinline__ float unpack_sc(unsigned p) {
  unsigned mono = p & 0xFFFFE000u;
  unsigned ub = (mono & 0x80000000u) ? (mono ^ 0x80000000u) : ~mono;
  return __uint_as_float(ub);
}

// ---------------------------------------------------------------------------
// Generic bf16 MFMA GEMM: C[M,N] = epilogue(A[M,K] @ B^T[N,K] + bias)
// A row-major (lda), B stored [n][k] (ldb) unless BT: B raw [k][n] (ldb), k<Kb.
// EPI: 0 f32 alpha*acc+bias | 1 bf16 acc+bias | 2 bf16 gelu(acc+bias)
//      3 f32 add+acc+bias (residual) | 4 f32 alpha*acc | 5 bf16 acc+add(optional)
// ---------------------------------------------------------------------------
template <int EPI, bool BT>
__global__ __launch_bounds__(256) void gemm_k(
    const u16* __restrict__ A, int lda, long sA,
    const u16* __restrict__ B, int ldb, long sB, int Kb,
    const float* __restrict__ bias,
    const float* __restrict__ add, long sAdd,
    void* __restrict__ Cv, int ldc, long sC,
    int M, int N, int K, float alpha) {
  __shared__ u16 As[128][40];
  __shared__ u16 Bs[64][40];
  const int tid = threadIdx.x;
  const int m0 = blockIdx.x * 128, n0 = blockIdx.y * 64;
  const int bz = blockIdx.z;
  A += (long)bz * sA;
  B += (long)bz * sB;
  const int w = tid >> 6, lane = tid & 63;
  const int wr = w & 1, wc = w >> 1;
  const int lr = lane & 15, lk = (lane >> 4) * 8;
  floatx4 zf = {0.f, 0.f, 0.f, 0.f};
  floatx4 acc[4][2];
#pragma unroll
  for (int i = 0; i < 4; i++)
#pragma unroll
    for (int j = 0; j < 2; j++) acc[i][j] = zf;

  for (int k0 = 0; k0 < K; k0 += 32) {
#pragma unroll
    for (int t = 0; t < 2; t++) {
      int task = tid + t * 256;
      int r = task >> 2, k8 = (task & 3) * 8;
      short8 v = {0, 0, 0, 0, 0, 0, 0, 0};
      if (m0 + r < M) v = *(const short8*)(A + (long)(m0 + r) * lda + k0 + k8);
      *(short8*)&As[r][k8] = v;
    }
    if (!BT) {
      int r = tid >> 2, k8 = (tid & 3) * 8;
      short8 v = {0, 0, 0, 0, 0, 0, 0, 0};
      if (n0 + r < N) v = *(const short8*)(B + (long)(n0 + r) * ldb + k0 + k8);
      *(short8*)&Bs[r][k8] = v;
    } else {
#pragma unroll
      for (int t = 0; t < 8; t++) {
        int task = tid + t * 256;
        int n = task & 63, kk = task >> 6;
        u16 v = 0;
        if (k0 + kk < Kb && n0 + n < N) v = B[(long)(k0 + kk) * ldb + n0 + n];
        Bs[n][kk] = v;
      }
    }
    __syncthreads();
    short8 af[4], bfr[2];
#pragma unroll
    for (int i = 0; i < 4; i++) af[i] = *(const short8*)&As[wr * 64 + i * 16 + lr][lk];
#pragma unroll
    for (int j = 0; j < 2; j++) bfr[j] = *(const short8*)&Bs[wc * 32 + j * 16 + lr][lk];
#pragma unroll
    for (int i = 0; i < 4; i++)
#pragma unroll
      for (int j = 0; j < 2; j++)
        acc[i][j] = __builtin_amdgcn_mfma_f32_16x16x32_bf16(af[i], bfr[j], acc[i][j], 0, 0, 0);
    __syncthreads();
  }
#pragma unroll
  for (int i = 0; i < 4; i++) {
#pragma unroll
    for (int j = 0; j < 2; j++) {
      int gn = n0 + wc * 32 + j * 16 + lr;
#pragma unroll
      for (int r = 0; r < 4; r++) {
        int gm = m0 + wr * 64 + i * 16 + (lane >> 4) * 4 + r;
        if (gm < M && gn < N) {
          float v = acc[i][j][r];
          float bi = bias ? bias[gn] : 0.f;
          long co = (long)bz * sC + (long)gm * ldc + gn;
          if (EPI == 0) {
            ((float*)Cv)[co] = v * alpha + bi;
          } else if (EPI == 1) {
            ((u16*)Cv)[co] = f2bf(v + bi);
          } else if (EPI == 2) {
            float t = v + bi;
            float g = 0.5f * t * (1.f + tanhf(0.7978845608028654f * (t + 0.044715f * t * t * t)));
            ((u16*)Cv)[co] = f2bf(g);
          } else if (EPI == 3) {
            ((float*)Cv)[co] = add[(long)gm * ldc + gn] + v + bi;
          } else if (EPI == 4) {
            ((float*)Cv)[co] = v * alpha;
          } else {
            float t = v + (add ? add[(long)bz * sAdd + (long)gm * ldc + gn] : 0.f);
            ((u16*)Cv)[co] = f2bf(t);
          }
        }
      }
    }
  }
}

// ---------------------------------------------------------------------------
// Fused LayerNorm + GEMM for K = D = 128 (single staging phase, no k-loop).
// ---------------------------------------------------------------------------
template <int EPI>
__global__ __launch_bounds__(256) void lngemm_k(
    const float* __restrict__ H, const float* __restrict__ g,
    const float* __restrict__ bb, const u16* __restrict__ B,
    const float* __restrict__ bias, u16* __restrict__ C, int ldc, int N) {
  __shared__ u16 As[128][136];
  __shared__ u16 Bs[64][136];
  __shared__ float stats[128][4];
  const int tid = threadIdx.x;
  const int m0 = blockIdx.x * 128, n0 = blockIdx.y * 64;
#pragma unroll
  for (int t = 0; t < 4; t++) {
    int task = tid + t * 256;
    int rb = task >> 4, c8 = (task & 15) * 8;
    short8 v = *(const short8*)(B + (long)(n0 + rb) * 128 + c8);
    *(short8*)&Bs[rb][c8] = v;
  }
  const int row = tid >> 1, half = tid & 1;
  float4 xv[16];
  const float* hp = H + (long)(m0 + row) * 128 + half * 64;
  float s1 = 0.f, s2 = 0.f;
#pragma unroll
  for (int t = 0; t < 16; t++) {
    xv[t] = *(const float4*)(hp + t * 4);
    s1 += xv[t].x + xv[t].y + xv[t].z + xv[t].w;
    s2 += xv[t].x * xv[t].x + xv[t].y * xv[t].y + xv[t].z * xv[t].z + xv[t].w * xv[t].w;
  }
  stats[row][half * 2] = s1;
  stats[row][half * 2 + 1] = s2;
  __syncthreads();
  float fs1 = stats[row][0] + stats[row][2];
  float fs2 = stats[row][1] + stats[row][3];
  float mu = fs1 * 0.0078125f;
  float var = fs2 * 0.0078125f - mu * mu;
  float rs = rsqrtf(var + 1e-5f);
  const float* gp = g + half * 64;
  const float* bp = bb + half * 64;
#pragma unroll
  for (int t = 0; t < 16; t++) {
    float4 gv = *(const float4*)(gp + t * 4);
    float4 bv = *(const float4*)(bp + t * 4);
    ushort4 o;
    o.x = f2bf((xv[t].x - mu) * rs * gv.x + bv.x);
    o.y = f2bf((xv[t].y - mu) * rs * gv.y + bv.y);
    o.z = f2bf((xv[t].z - mu) * rs * gv.z + bv.z);
    o.w = f2bf((xv[t].w - mu) * rs * gv.w + bv.w);
    *(ushort4*)&As[row][half * 64 + t * 4] = o;
  }
  __syncthreads();
  const int w = tid >> 6, lane = tid & 63;
  const int wr = w & 1, wc = w >> 1;
  const int lr = lane & 15, lk = (lane >> 4) * 8;
  floatx4 zf = {0.f, 0.f, 0.f, 0.f};
  floatx4 acc[4][2];
#pragma unroll
  for (int i = 0; i < 4; i++)
#pragma unroll
    for (int j = 0; j < 2; j++) acc[i][j] = zf;
#pragma unroll
  for (int kc = 0; kc < 4; kc++) {
    short8 afr[4], bfr[2];
#pragma unroll
    for (int i = 0; i < 4; i++) afr[i] = *(const short8*)&As[wr * 64 + i * 16 + lr][kc * 32 + lk];
#pragma unroll
    for (int j = 0; j < 2; j++) bfr[j] = *(const short8*)&Bs[wc * 32 + j * 16 + lr][kc * 32 + lk];
#pragma unroll
    for (int i = 0; i < 4; i++)
#pragma unroll
      for (int j = 0; j < 2; j++)
        acc[i][j] = __builtin_amdgcn_mfma_f32_16x16x32_bf16(afr[i], bfr[j], acc[i][j], 0, 0, 0);
  }
#pragma unroll
  for (int i = 0; i < 4; i++) {
#pragma unroll
    for (int j = 0; j < 2; j++) {
      int gn = n0 + wc * 32 + j * 16 + lr;
#pragma unroll
      for (int r = 0; r < 4; r++) {
        int gm = m0 + wr * 64 + i * 16 + (lane >> 4) * 4 + r;
        float v = acc[i][j][r] + bias[gn];
        if (EPI == 2) {
          v = 0.5f * v * (1.f + tanhf(0.7978845608028654f * (v + 0.044715f * v * v * v)));
        }
        C[(long)gm * ldc + gn] = f2bf(v);
      }
    }
  }
}

// ---------------------------------------------------------------------------
// Fused attention for non-kNN layers: sim -> softmax -> P@V, one kernel.
// Block: 28 q-rows of one batch. grid (7, 32). ~63KB LDS, 2 blocks/CU.
// ---------------------------------------------------------------------------
__global__ __launch_bounds__(256) void attn_k(const u16* __restrict__ qkv,
                                              u16* __restrict__ obf) {
  __shared__ u16 qs[32][136];
  __shared__ float sc[32][228];
  __shared__ u16 P[32][232];
  __shared__ u16 Vs[128][40];
  const int tid = threadIdx.x, w = tid >> 6, lane = tid & 63;
  const int b = blockIdx.y, n0 = blockIdx.x * 28;
  const u16* qb = qkv + (long)b * 196 * 384;
  // stage q rows n0..n0+27 (zero-pad to 32)
  {
    int r = tid >> 3, c0 = (tid & 7) * 16;
    short8 z = {0, 0, 0, 0, 0, 0, 0, 0};
    short8 v0 = z, v1 = z;
    if (r < 28) {
      const u16* src = qb + (long)(n0 + r) * 384 + c0;
      v0 = *(const short8*)src;
      v1 = *(const short8*)(src + 8);
    }
    *(short8*)&qs[r][c0] = v0;
    *(short8*)&qs[r][c0 + 8] = v1;
  }
  __syncthreads();
  const int lr = lane & 15, lq = lane >> 4, lk = lq * 8;
  short8 qf[2][4];
#pragma unroll
  for (int m = 0; m < 2; m++)
#pragma unroll
    for (int kc = 0; kc < 4; kc++)
      qf[m][kc] = *(const short8*)&qs[m * 16 + lr][kc * 32 + lk];

  // --- score phase: 13 key-chunks of 16, cyclic over waves ---
  const u16* kb = qb + 128;
#pragma unroll 1
  for (int c = w; c < 13; c += 4) {
    int key0 = c * 16;
    short8 kf[4];
    const u16* kp = kb + (long)(key0 + lr) * 384;  // rows >=196 masked later
#pragma unroll
    for (int kc = 0; kc < 4; kc++) kf[kc] = *(const short8*)(kp + kc * 32 + lk);
#pragma unroll
    for (int m = 0; m < 2; m++) {
      floatx4 acc = {0.f, 0.f, 0.f, 0.f};
#pragma unroll
      for (int kc = 0; kc < 4; kc++)
        acc = __builtin_amdgcn_mfma_f32_16x16x32_bf16(qf[m][kc], kf[kc], acc, 0, 0, 0);
#pragma unroll
      for (int j = 0; j < 4; j++) sc[m * 16 + lq * 4 + j][key0 + lr] = acc[j];
    }
  }
  __syncthreads();
  // --- softmax: 8 threads per row, 28 cols each ---
  {
    int r = tid >> 3, j0 = (tid & 7) * 28;
    if (r < 28) {
      float v[28];
      float mx = -1e30f;
#pragma unroll
      for (int i = 0; i < 28; i++) {
        int j = j0 + i;
        v[i] = (j < 196) ? sc[r][j] * ATT_SCALE : -1e30f;
        mx = fmaxf(mx, v[i]);
      }
#pragma unroll
      for (int m = 1; m <= 4; m <<= 1) mx = fmaxf(mx, __shfl_xor(mx, m));
      float s = 0.f;
#pragma unroll
      for (int i = 0; i < 28; i++) {
        v[i] = (j0 + i < 196) ? expf(v[i] - mx) : 0.f;
        s += v[i];
      }
#pragma unroll
      for (int m = 1; m <= 4; m <<= 1) s += __shfl_xor(s, m);
      float inv = 1.f / s;
#pragma unroll
      for (int i = 0; i < 28; i++) P[r][j0 + i] = f2bf(v[i] * inv);
    } else {
#pragma unroll
      for (int i = 0; i < 28; i++) P[r][j0 + i] = 0;
    }
  }
  __syncthreads();
  // --- PV: O(32x128) = P(32x224) @ V(224x128) ---
  const int mtile = w & 1, nh = w >> 1;
  floatx4 acc[4];
#pragma unroll
  for (int t = 0; t < 4; t++) acc[t] = (floatx4){0.f, 0.f, 0.f, 0.f};
  const u16* vb = qb + 256;
#pragma unroll 1
  for (int kc = 0; kc < 7; kc++) {
    {
      int tok = tid >> 3, d0 = (tid & 7) * 16;
      int gt = kc * 32 + tok;
      short8 z = {0, 0, 0, 0, 0, 0, 0, 0};
      short8 v0 = z, v1 = z;
      if (gt < 196) {
        const u16* vp = vb + (long)gt * 384 + d0;
        v0 = *(const short8*)vp;
        v1 = *(const short8*)(vp + 8);
      }
      u16 tmp[16];
      *(short8*)tmp = v0;
      *(short8*)(tmp + 8) = v1;
#pragma unroll
      for (int i = 0; i < 16; i++) Vs[d0 + i][tok] = tmp[i];
    }
    __syncthreads();
    short8 pf = *(const short8*)&P[mtile * 16 + lr][kc * 32 + lk];
#pragma unroll
    for (int t = 0; t < 4; t++) {
      short8 vf = *(const short8*)&Vs[nh * 64 + t * 16 + lr][lk];
      acc[t] = __builtin_amdgcn_mfma_f32_16x16x32_bf16(pf, vf, acc[t], 0, 0, 0);
    }
    __syncthreads();
  }
#pragma unroll
  for (int t = 0; t < 4; t++) {
    int gn = nh * 64 + t * 16 + lr;
#pragma unroll
    for (int r = 0; r < 4; r++) {
      int rloc = mtile * 16 + lq * 4 + r;
      if (rloc < 28) obf[((long)b * 196 + n0 + rloc) * 128 + gn] = f2bf(acc[t][r]);
    }
  }
}

// ---------------------------------------------------------------------------
// weight convert + transpose to bf16 [n][k] layouts
// ---------------------------------------------------------------------------
__global__ __launch_bounds__(256) void cvtw_k(
    const float* __restrict__ pw, const float* __restrict__ qw,
    const float* __restrict__ ow, const float* __restrict__ f1,
    const float* __restrict__ f2, u16* __restrict__ wbf) {
  int idx = blockIdx.x * 256 + threadIdx.x;
  float v;
  if (idx < 98304) {
    int n = idx / 768, k = idx % 768;
    v = pw[k * 128 + n];
  } else if (idx < 442368) {
    int rel = idx - 98304;
    int i = rel / 49152, r = rel % 49152, n = r / 128, k = r % 128;
    v = qw[((long)i * 128 + k) * 384 + n];
  } else if (idx < 557056) {
    int rel = idx - 442368;
    int i = rel / 16384, r = rel % 16384, n = r / 128, k = r % 128;
    v = ow[((long)i * 128 + k) * 128 + n];
  } else if (idx < 1015808) {
    int rel = idx - 557056;
    int i = rel / 65536, r = rel % 65536, n = r / 128, k = r % 128;
    v = f1[((long)i * 128 + k) * 512 + n];
  } else {
    int rel = idx - 1015808;
    int i = rel / 65536, r = rel % 65536, n = r / 512, k = r % 512;
    v = f2[((long)i * 512 + k) * 128 + n];
  }
  wbf[idx] = f2bf(v);
}

// patchify x(32,3,224,224) -> p_bf(32,196,768) bf16
__global__ __launch_bounds__(256) void patchify_k(const float* __restrict__ x,
                                                  u16* __restrict__ p) {
  long idx = (long)blockIdx.x * 256 + threadIdx.x;
  int f = (int)(idx % 768);
  long bn = idx / 768;
  int n = (int)(bn % 196);
  int b = (int)(bn / 196);
  int c = f >> 8, ri = (f >> 4) & 15, cj = f & 15;
  int ph = n / 14, pw = n % 14;
  float v = x[(((long)b * 3 + c) * 224 + ph * 16 + ri) * 224 + pw * 16 + cj];
  p[idx] = f2bf(v);
}

// joint softmax over [32 memory scores | 196 local sims]  (kNN layer)
__global__ __launch_bounds__(256) void knn_softmax_k(
    const float* __restrict__ sim, const float* __restrict__ mvals,
    u16* __restrict__ p, float* __restrict__ am) {
  int row = blockIdx.x * 4 + (threadIdx.x >> 6);
  int lane = threadIdx.x & 63;
  const float* sr = sim + (long)row * 224;
  float v[4];
#pragma unroll
  for (int t = 0; t < 4; t++) {
    int j = t * 64 + lane;
    v[t] = (j < 196) ? sr[j] : -1e30f;
  }
  float mvv = (lane < 32) ? mvals[(long)row * 32 + lane] : -1e30f;
  float mx = wmaxr(fmaxf(fmaxf(fmaxf(v[0], v[1]), fmaxf(v[2], v[3])), mvv));
  float e[4], s = 0.f;
#pragma unroll
  for (int t = 0; t < 4; t++) {
    int j = t * 64 + lane;
    e[t] = (j < 196) ? expf(v[t] - mx) : 0.f;
    s += e[t];
  }
  float em = (lane < 32) ? expf(mvv - mx) : 0.f;
  s = wsum(s + em);
  float inv = 1.f / s;
  u16* pr = p + (long)row * 224;
#pragma unroll
  for (int t = 0; t < 4; t++) {
    int j = t * 64 + lane;
    if (j < 224) pr[j] = f2bf(e[t] * inv);
  }
  if (lane < 32) am[(long)row * 32 + lane] = em * inv;
}

// ---------------------------------------------------------------------------
// msim + streaming top-k, v3: keys as MFMA A-operand, queries as B-operand.
// C layout => lane owns one query column + 4 key rows: scores arrive in the
// exact lane that maintains the query's top-8 list. No LDS scratch, no shfl.
// Next-chunk key data prefetched into registers during the sort.
// grid (8 key-splits, 4 row-splits of 49, 32 batch).
// ---------------------------------------------------------------------------
__global__ __launch_bounds__(256) void msim_topk_k(
    const u16* __restrict__ qkv, const float* __restrict__ knnk,
    unsigned* __restrict__ cand) {
  __shared__ u16 qs[64][136];
  const int tid = threadIdx.x, w = tid >> 6, lane = tid & 63;
  const int b = blockIdx.z, n0 = blockIdx.y * 49, kq0 = blockIdx.x * 1024;
  const u16* qb = qkv + (long)b * 196 * 384;
#pragma unroll
  for (int t = 0; t < 4; t++) {
    int task = tid + t * 256;
    int r = task >> 4, c8 = (task & 15) * 8;
    short8 v = {0, 0, 0, 0, 0, 0, 0, 0};
    if (r < 49) v = *(const short8*)(qb + (long)(n0 + r) * 384 + c8);
    *(short8*)&qs[r][c8] = v;
  }
  __syncthreads();
  const int lr = lane & 15, lq = lane >> 4, lk = lq * 8;
  short8 qf[4][4];  // B-operand: queries
#pragma unroll
  for (int s = 0; s < 4; s++)
#pragma unroll
    for (int kc = 0; kc < 4; kc++)
      qf[s][kc] = *(const short8*)&qs[s * 16 + lr][kc * 32 + lk];

  unsigned st[4][8];
#pragma unroll
  for (int s = 0; s < 4; s++)
#pragma unroll
    for (int t = 0; t < 8; t++) st[s][t] = 0u;

  const float* kbase = knnk + ((long)b * 8192 + kq0 + lr) * 128 + lk;

  float4 raw[8];
  {
    const float* kp = kbase + (long)(w * 16) * 128;
#pragma unroll
    for (int kc = 0; kc < 4; kc++) {
      raw[kc * 2] = *(const float4*)(kp + kc * 32);
      raw[kc * 2 + 1] = *(const float4*)(kp + kc * 32 + 4);
    }
  }
#pragma unroll 1
  for (int c = 0; c < 16; c++) {
    float4 nraw[8];
    if (c < 15) {
      const float* kp = kbase + (long)(((c + 1) * 4 + w) * 16) * 128;
#pragma unroll
      for (int kc = 0; kc < 4; kc++) {
        nraw[kc * 2] = *(const float4*)(kp + kc * 32);
        nraw[kc * 2 + 1] = *(const float4*)(kp + kc * 32 + 4);
      }
    }
    short8 kf[4];  // A-operand: keys
#pragma unroll
    for (int kc = 0; kc < 4; kc++) {
      int4 iv;
      iv.x = (int)bfpack(raw[kc * 2].x, raw[kc * 2].y);
      iv.y = (int)bfpack(raw[kc * 2].z, raw[kc * 2].w);
      iv.z = (int)bfpack(raw[kc * 2 + 1].x, raw[kc * 2 + 1].y);
      iv.w = (int)bfpack(raw[kc * 2 + 1].z, raw[kc * 2 + 1].w);
      kf[kc] = *(short8*)&iv;
    }
    const int kb = kq0 + (c * 4 + w) * 16 + lq * 4;
#pragma unroll
    for (int s = 0; s < 4; s++) {
      floatx4 acc = {0.f, 0.f, 0.f, 0.f};
#pragma unroll
      for (int kc = 0; kc < 4; kc++)
        acc = __builtin_amdgcn_mfma_f32_16x16x32_bf16(kf[kc], qf[s][kc], acc, 0, 0, 0);
#pragma unroll
      for (int r = 0; r < 4; r++) {
        float v = acc[r] * ATT_SCALE;
        unsigned u = __float_as_uint(v);
        unsigned mono = u ^ ((unsigned)((int)u >> 31) | 0x80000000u);
        unsigned x = (mono & 0xFFFFE000u) | (unsigned)(kb + r);
#pragma unroll
        for (int t = 0; t < 8; t++) {
          unsigned mx = max(st[s][t], x);
          x = min(st[s][t], x);
          st[s][t] = mx;
        }
      }
    }
    if (c < 15) {
#pragma unroll
      for (int i = 0; i < 8; i++) raw[i] = nraw[i];
    }
  }
#pragma unroll
  for (int s = 0; s < 4; s++) {
    int rloc = s * 16 + lr;
    if (rloc < 49) {
      unsigned* dst = cand + ((long)b * 196 + n0 + rloc) * 1024 + blockIdx.x * 128 + w * 32 + lq * 8;
#pragma unroll
      for (int t = 0; t < 8; t++) dst[t] = st[s][t];
    }
  }
}

// merge 1024 candidates/row -> exact top-32 of the candidate set
__global__ __launch_bounds__(256) void topk_merge_k(
    const unsigned* __restrict__ cand, float* __restrict__ mvals,
    int* __restrict__ midx) {
  int row = blockIdx.x * 4 + (threadIdx.x >> 6);
  int lane = threadIdx.x & 63;
  const unsigned* cr = cand + (long)row * 1024;
  unsigned c[16];
#pragma unroll
  for (int t = 0; t < 16; t++) c[t] = cr[t * 64 + lane];
  float* mv = mvals + (long)row * 32;
  int* mi = midx + (long)row * 32;
  for (int r = 0; r < 32; r++) {
    unsigned lm = c[0];
#pragma unroll
    for (int t = 1; t < 16; t++) lm = max(lm, c[t]);
    unsigned gm = lm;
#pragma unroll
    for (int m = 32; m >= 1; m >>= 1) gm = max(gm, (unsigned)__shfl_xor((int)gm, m));
    bool has = false;
#pragma unroll
    for (int t = 0; t < 16; t++)
      if (!has && c[t] == gm) {
        c[t] = 0u;
        has = true;
      }
    if (has) {
      mv[r] = unpack_sc(gm);
      mi[r] = (int)(gm & 0x1FFFu);
    }
  }
}

// o32[row][d] = sum_k am[k] * knn_v[b][midx[k]][d]
__global__ __launch_bounds__(256) void knn_gather_k(
    const float* __restrict__ am, const int* __restrict__ ix,
    const float* __restrict__ kv, float* __restrict__ o32) {
  int row = blockIdx.x * 4 + (threadIdx.x >> 6);
  int lane = threadIdx.x & 63;
  int b = row / 196;
  const float* vb = kv + (long)b * 8192 * 128;
  const float* ar = am + (long)row * 32;
  const int* xr = ix + (long)row * 32;
  float a0 = 0.f, a1 = 0.f;
#pragma unroll 4
  for (int k = 0; k < 32; k++) {
    float wv = ar[k];
    int id = xr[k];
    float2 v = *(const float2*)&vb[(long)id * 128 + lane * 2];
    a0 += wv * v.x;
    a1 += wv * v.y;
  }
  float2 o;
  o.x = a0;
  o.y = a1;
  *(float2*)&o32[(long)row * 128 + lane * 2] = o;
}

// final LN + token-mean + head GEMM. one block per batch.
__global__ __launch_bounds__(256) void final_k(
    const float* __restrict__ h, const float* __restrict__ g,
    const float* __restrict__ bb, const float* __restrict__ hw,
    const float* __restrict__ hb, float* __restrict__ out) {
  __shared__ float fw[4][128];
  __shared__ float feats[128];
  int tid = threadIdx.x, w = tid >> 6, lane = tid & 63;
  int b = blockIdx.x;
  float2 gv = *(const float2*)&g[lane * 2];
  float2 bv = *(const float2*)&bb[lane * 2];
  float a0 = 0.f, a1 = 0.f;
  for (int r = w; r < 196; r += 4) {
    float2 x = *(const float2*)&h[((long)b * 196 + r) * 128 + lane * 2];
    float mu = wsum(x.x + x.y) * 0.0078125f;
    float d0 = x.x - mu, d1 = x.y - mu;
    float var = wsum(d0 * d0 + d1 * d1) * 0.0078125f;
    float rs = 1.f / sqrtf(var + 1e-5f);
    a0 += d0 * rs * gv.x + bv.x;
    a1 += d1 * rs * gv.y + bv.y;
  }
  fw[w][lane * 2] = a0;
  fw[w][lane * 2 + 1] = a1;
  __syncthreads();
  if (tid < 128) feats[tid] = (fw[0][tid] + fw[1][tid] + fw[2][tid] + fw[3][tid]) * (1.f / 196.f);
  __syncthreads();
  for (int o = tid; o < 1000; o += 256) {
    float acc = hb[o];
    for (int d = 0; d < 128; d++) acc += feats[d] * hw[d * 1000 + o];
    out[(long)b * 1000 + o] = acc;
  }
}

// ---------------------------------------------------------------------------
extern "C" void kernel_launch(void* const* d_in, const int* in_sizes, int n_in,
                              void* d_out, int out_size, void* d_ws, size_t ws_size,
                              hipStream_t stream) {
  (void)in_sizes; (void)n_in; (void)out_size; (void)ws_size;
  const float* x       = (const float*)d_in[0];
  const float* patch_w = (const float*)d_in[1];
  const float* patch_b = (const float*)d_in[2];
  const float* ln1_g   = (const float*)d_in[3];
  const float* ln1_b   = (const float*)d_in[4];
  const float* qkv_w   = (const float*)d_in[5];
  const float* qkv_b   = (const float*)d_in[6];
  const float* out_w   = (const float*)d_in[7];
  const float* out_b   = (const float*)d_in[8];
  const float* ln2_g   = (const float*)d_in[9];
  const float* ln2_b   = (const float*)d_in[10];
  const float* ff1_w   = (const float*)d_in[11];
  const float* ff1_b   = (const float*)d_in[12];
  const float* ff2_w   = (const float*)d_in[13];
  const float* ff2_b   = (const float*)d_in[14];
  const float* lnf_g   = (const float*)d_in[15];
  const float* lnf_b   = (const float*)d_in[16];
  const float* knn_k   = (const float*)d_in[17];
  const float* knn_v   = (const float*)d_in[18];
  const float* head_w  = (const float*)d_in[19];
  const float* head_b  = (const float*)d_in[20];

  char* ws = (char*)d_ws;
  size_t off = 0;
  u16* wbf = (u16*)(ws + off);        off += 2949120;
  u16* p_bf = (u16*)(ws + off);       off += 9633792;
  float* h = (float*)(ws + off);      off += 3211264;
  u16* qkvb = (u16*)(ws + off);       off += 4816896;
  u16* g_bf = (u16*)(ws + off);       off += 6422528;
  u16* o_bf = (u16*)(ws + off);       off += 1605632;
  float* o32 = (float*)(ws + off);    off += 3211264;
  float* simf = (float*)(ws + off);   off += 5619712;
  u16* pbf = (u16*)(ws + off);        off += 2809856;
  unsigned* cand = (unsigned*)(ws + off); off += 25690112;
  float* mvals = (float*)(ws + off);  off += 802816;
  int* midx = (int*)(ws + off);       off += 802816;
  float* amf = (float*)(ws + off);    off += 802816;

  dim3 blk(256);
  cvtw_k<<<5760, blk, 0, stream>>>(patch_w, qkv_w, out_w, ff1_w, ff2_w, wbf);
  patchify_k<<<18816, blk, 0, stream>>>(x, p_bf);
  gemm_k<0, false><<<dim3(49, 2, 1), blk, 0, stream>>>(
      p_bf, 768, 0, wbf, 768, 0, 768, patch_b, nullptr, 0, h, 128, 0, 6272, 128, 768, 1.f);

  for (int i = 0; i < 7; i++) {
    lngemm_k<1><<<dim3(49, 6), blk, 0, stream>>>(
        h, ln1_g + i * 128, ln1_b + i * 128, wbf + 98304 + i * 49152,
        qkv_b + i * 384, qkvb, 384, 384);
    if (i == 6) {
      msim_topk_k<<<dim3(8, 4, 32), blk, 0, stream>>>(qkvb, knn_k, cand);
      topk_merge_k<<<1568, blk, 0, stream>>>(cand, mvals, midx);
      gemm_k<4, false><<<dim3(2, 4, 32), blk, 0, stream>>>(
          qkvb, 384, (long)196 * 384, qkvb + 128, 384, (long)196 * 384, 128,
          nullptr, nullptr, 0, simf, 224, (long)196 * 224, 196, 196, 128, ATT_SCALE);
      knn_softmax_k<<<1568, blk, 0, stream>>>(simf, mvals, pbf, amf);
      knn_gather_k<<<1568, blk, 0, stream>>>(amf, midx, knn_v, o32);
      gemm_k<5, true><<<dim3(2, 2, 32), blk, 0, stream>>>(
          pbf, 224, (long)196 * 224, qkvb + 256, 384, (long)196 * 384, 196,
          nullptr, o32, (long)196 * 128, o_bf, 128, (long)196 * 128, 196, 128, 224, 1.f);
    } else {
      attn_k<<<dim3(7, 32), blk, 0, stream>>>(qkvb, o_bf);
    }
    gemm_k<3, false><<<dim3(49, 2, 1), blk, 0, stream>>>(
        o_bf, 128, 0, wbf + 442368 + i * 16384, 128, 0, 128, out_b + i * 128,
        h, 0, h, 128, 0, 6272, 128, 128, 1.f);
    lngemm_k<2><<<dim3(49, 8), blk, 0, stream>>>(
        h, ln2_g + i * 128, ln2_b + i * 128, wbf + 557056 + i * 65536,
        ff1_b + i * 512, g_bf, 512, 512);
    gemm_k<3, false><<<dim3(49, 2, 1), blk, 0, stream>>>(
        g_bf, 512, 0, wbf + 1015808 + i * 65536, 512, 0, 512, ff2_b + i * 128,
        h, 0, h, 128, 0, 6272, 128, 512, 1.f);
  }
  final_k<<<32, blk, 0, stream>>>(h, lnf_g, lnf_b, head_w, head_b, (float*)d_out);
}

// Round 4
// 917.608 us; speedup vs baseline: 1.4011x; 1.1539x over previous
//
#include <hip/hip_runtime.h>
#include <hip/hip_fp16.h>

typedef unsigned short u16;
typedef __attribute__((ext_vector_type(8))) short short8;
typedef __attribute__((ext_vector_type(4))) float floatx4;

#define ATT_SCALE 0.08838834764831845f

__device__ __forceinline__ u16 f2bf(float f) {
  unsigned u = __float_as_uint(f);
  u += 0x7FFFu + ((u >> 16) & 1u);
  return (u16)(u >> 16);
}

__device__ __forceinline__ unsigned bfpack(float a, float b) {
  unsigned ua = __float_as_uint(a);
  ua += 0x7FFFu + ((ua >> 16) & 1u);
  unsigned ub = __float_as_uint(b);
  ub += 0x7FFFu + ((ub >> 16) & 1u);
  return __builtin_amdgcn_perm(ub, ua, 0x07060302u);
}

__device__ __forceinline__ float wsum(float v) {
#pragma unroll
  for (int m = 32; m >= 1; m >>= 1) v += __shfl_xor(v, m);
  return v;
}
__device__ __forceinline__ float wmaxr(float v) {
#pragma unroll
  for (int m = 32; m >= 1; m >>= 1) v = fmaxf(v, __shfl_xor(v, m));
  return v;
}

// packed candidate: monotone-f32 bits [31:13] | key idx (13 bits); scale
// applied at unpack (monotone => ranking unchanged).
__device__ __forceinline__ float unpack_sc(unsigned p) {
  unsigned mono = p & 0xFFFFE000u;
  unsigned ub = (mono & 0x80000000u) ? (mono ^ 0x80000000u) : ~mono;
  return __uint_as_float(ub);
}

__device__ __forceinline__ float gelu_f(float t) {
  return 0.5f * t * (1.f + tanhf(0.7978845608028654f * (t + 0.044715f * t * t * t)));
}

// ---------------------------------------------------------------------------
// Generic bf16 MFMA GEMM (used for patch embed + knn-layer sim/PV).
// EPI: 0 f32 alpha*acc+bias | 4 f32 alpha*acc | 5 bf16 acc+add(optional)
// ---------------------------------------------------------------------------
template <int EPI, bool BT>
__global__ __launch_bounds__(256) void gemm_k(
    const u16* __restrict__ A, int lda, long sA,
    const u16* __restrict__ B, int ldb, long sB, int Kb,
    const float* __restrict__ bias,
    const float* __restrict__ add, long sAdd,
    void* __restrict__ Cv, int ldc, long sC,
    int M, int N, int K, float alpha) {
  __shared__ u16 As[128][40];
  __shared__ u16 Bs[64][40];
  const int tid = threadIdx.x;
  const int m0 = blockIdx.x * 128, n0 = blockIdx.y * 64;
  const int bz = blockIdx.z;
  A += (long)bz * sA;
  B += (long)bz * sB;
  const int w = tid >> 6, lane = tid & 63;
  const int wr = w & 1, wc = w >> 1;
  const int lr = lane & 15, lk = (lane >> 4) * 8;
  floatx4 zf = {0.f, 0.f, 0.f, 0.f};
  floatx4 acc[4][2];
#pragma unroll
  for (int i = 0; i < 4; i++)
#pragma unroll
    for (int j = 0; j < 2; j++) acc[i][j] = zf;

  for (int k0 = 0; k0 < K; k0 += 32) {
#pragma unroll
    for (int t = 0; t < 2; t++) {
      int task = tid + t * 256;
      int r = task >> 2, k8 = (task & 3) * 8;
      short8 v = {0, 0, 0, 0, 0, 0, 0, 0};
      if (m0 + r < M) v = *(const short8*)(A + (long)(m0 + r) * lda + k0 + k8);
      *(short8*)&As[r][k8] = v;
    }
    if (!BT) {
      int r = tid >> 2, k8 = (tid & 3) * 8;
      short8 v = {0, 0, 0, 0, 0, 0, 0, 0};
      if (n0 + r < N) v = *(const short8*)(B + (long)(n0 + r) * ldb + k0 + k8);
      *(short8*)&Bs[r][k8] = v;
    } else {
#pragma unroll
      for (int t = 0; t < 8; t++) {
        int task = tid + t * 256;
        int n = task & 63, kk = task >> 6;
        u16 v = 0;
        if (k0 + kk < Kb && n0 + n < N) v = B[(long)(k0 + kk) * ldb + n0 + n];
        Bs[n][kk] = v;
      }
    }
    __syncthreads();
    short8 af[4], bfr[2];
#pragma unroll
    for (int i = 0; i < 4; i++) af[i] = *(const short8*)&As[wr * 64 + i * 16 + lr][lk];
#pragma unroll
    for (int j = 0; j < 2; j++) bfr[j] = *(const short8*)&Bs[wc * 32 + j * 16 + lr][lk];
#pragma unroll
    for (int i = 0; i < 4; i++)
#pragma unroll
      for (int j = 0; j < 2; j++)
        acc[i][j] = __builtin_amdgcn_mfma_f32_16x16x32_bf16(af[i], bfr[j], acc[i][j], 0, 0, 0);
    __syncthreads();
  }
#pragma unroll
  for (int i = 0; i < 4; i++) {
#pragma unroll
    for (int j = 0; j < 2; j++) {
      int gn = n0 + wc * 32 + j * 16 + lr;
#pragma unroll
      for (int r = 0; r < 4; r++) {
        int gm = m0 + wr * 64 + i * 16 + (lane >> 4) * 4 + r;
        if (gm < M && gn < N) {
          float v = acc[i][j][r];
          float bi = bias ? bias[gn] : 0.f;
          long co = (long)bz * sC + (long)gm * ldc + gn;
          if (EPI == 0) {
            ((float*)Cv)[co] = v * alpha + bi;
          } else if (EPI == 4) {
            ((float*)Cv)[co] = v * alpha;
          } else {
            float t = v + (add ? add[(long)bz * sAdd + (long)gm * ldc + gn] : 0.f);
            ((u16*)Cv)[co] = f2bf(t);
          }
        }
      }
    }
  }
}

// ---------------------------------------------------------------------------
// Fused LayerNorm + GEMM (layer-0 qkv only).
// ---------------------------------------------------------------------------
__global__ __launch_bounds__(256) void lngemm_k(
    const float* __restrict__ H, const float* __restrict__ g,
    const float* __restrict__ bb, const u16* __restrict__ B,
    const float* __restrict__ bias, u16* __restrict__ C, int ldc, int N) {
  __shared__ u16 As[128][136];
  __shared__ u16 Bs[64][136];
  __shared__ float stats[128][4];
  const int tid = threadIdx.x;
  const int m0 = blockIdx.x * 128, n0 = blockIdx.y * 64;
#pragma unroll
  for (int t = 0; t < 4; t++) {
    int task = tid + t * 256;
    int rb = task >> 4, c8 = (task & 15) * 8;
    short8 v = *(const short8*)(B + (long)(n0 + rb) * 128 + c8);
    *(short8*)&Bs[rb][c8] = v;
  }
  const int row = tid >> 1, half = tid & 1;
  float4 xv[16];
  const float* hp = H + (long)(m0 + row) * 128 + half * 64;
  float s1 = 0.f, s2 = 0.f;
#pragma unroll
  for (int t = 0; t < 16; t++) {
    xv[t] = *(const float4*)(hp + t * 4);
    s1 += xv[t].x + xv[t].y + xv[t].z + xv[t].w;
    s2 += xv[t].x * xv[t].x + xv[t].y * xv[t].y + xv[t].z * xv[t].z + xv[t].w * xv[t].w;
  }
  stats[row][half * 2] = s1;
  stats[row][half * 2 + 1] = s2;
  __syncthreads();
  float fs1 = stats[row][0] + stats[row][2];
  float fs2 = stats[row][1] + stats[row][3];
  float mu = fs1 * 0.0078125f;
  float var = fs2 * 0.0078125f - mu * mu;
  float rs = rsqrtf(var + 1e-5f);
  const float* gp = g + half * 64;
  const float* bp = bb + half * 64;
#pragma unroll
  for (int t = 0; t < 16; t++) {
    float4 gv = *(const float4*)(gp + t * 4);
    float4 bv = *(const float4*)(bp + t * 4);
    ushort4 o;
    o.x = f2bf((xv[t].x - mu) * rs * gv.x + bv.x);
    o.y = f2bf((xv[t].y - mu) * rs * gv.y + bv.y);
    o.z = f2bf((xv[t].z - mu) * rs * gv.z + bv.z);
    o.w = f2bf((xv[t].w - mu) * rs * gv.w + bv.w);
    *(ushort4*)&As[row][half * 64 + t * 4] = o;
  }
  __syncthreads();
  const int w = tid >> 6, lane = tid & 63;
  const int wr = w & 1, wc = w >> 1;
  const int lr = lane & 15, lk = (lane >> 4) * 8;
  floatx4 acc[4][2];
#pragma unroll
  for (int i = 0; i < 4; i++)
#pragma unroll
    for (int j = 0; j < 2; j++) acc[i][j] = (floatx4){0.f, 0.f, 0.f, 0.f};
#pragma unroll
  for (int kc = 0; kc < 4; kc++) {
    short8 afr[4], bfr[2];
#pragma unroll
    for (int i = 0; i < 4; i++) afr[i] = *(const short8*)&As[wr * 64 + i * 16 + lr][kc * 32 + lk];
#pragma unroll
    for (int j = 0; j < 2; j++) bfr[j] = *(const short8*)&Bs[wc * 32 + j * 16 + lr][kc * 32 + lk];
#pragma unroll
    for (int i = 0; i < 4; i++)
#pragma unroll
      for (int j = 0; j < 2; j++)
        acc[i][j] = __builtin_amdgcn_mfma_f32_16x16x32_bf16(afr[i], bfr[j], acc[i][j], 0, 0, 0);
  }
#pragma unroll
  for (int i = 0; i < 4; i++) {
#pragma unroll
    for (int j = 0; j < 2; j++) {
      int gn = n0 + wc * 32 + j * 16 + lr;
#pragma unroll
      for (int r = 0; r < 4; r++) {
        int gm = m0 + wr * 64 + i * 16 + (lane >> 4) * 4 + r;
        float v = acc[i][j][r] + bias[gn];
        C[(long)gm * ldc + gn] = f2bf(v);
      }
    }
  }
}

// ---------------------------------------------------------------------------
// blockB: o@out_w + out_b + h -> h2 (f32, nb==0) ; LN2(h2) ; @ff1 slice ->
// gelu -> g_bf.  grid (98 m-tiles of 64, 2 n-slices of 256).
// ---------------------------------------------------------------------------
__global__ __launch_bounds__(256) void blockB_k(
    const u16* __restrict__ obf, const u16* __restrict__ WoT,
    const float* __restrict__ ob, const float* __restrict__ h,
    const float* __restrict__ g2, const float* __restrict__ b2,
    const u16* __restrict__ W1T, const float* __restrict__ b1,
    float* __restrict__ h2, u16* __restrict__ gbf) {
  __shared__ u16 As[64][136];
  __shared__ u16 Bs[128][136];
  __shared__ float stats[64][2];
  const int tid = threadIdx.x, w = tid >> 6, lane = tid & 63;
  const int m0 = blockIdx.x * 64, nb = blockIdx.y;
  const int wr = w & 1, wc = w >> 1;
  const int lr = lane & 15, lq = lane >> 4, lk = lq * 8;
  if (tid < 128) stats[tid >> 1][tid & 1] = 0.f;
#pragma unroll
  for (int t = 0; t < 4; t++) {
    int u = tid + t * 256;
    int r = u >> 4, c8 = (u & 15) * 8;
    *(short8*)&As[r][c8] = *(const short8*)(obf + (long)(m0 + r) * 128 + c8);
  }
#pragma unroll
  for (int t = 0; t < 8; t++) {
    int u = tid + t * 256;
    int r = u >> 4, c8 = (u & 15) * 8;
    *(short8*)&Bs[r][c8] = *(const short8*)(WoT + (long)r * 128 + c8);
  }
  __syncthreads();
  floatx4 acc1[2][4];
#pragma unroll
  for (int i = 0; i < 2; i++)
#pragma unroll
    for (int j = 0; j < 4; j++) acc1[i][j] = (floatx4){0.f, 0.f, 0.f, 0.f};
#pragma unroll
  for (int kc = 0; kc < 4; kc++) {
    short8 a0 = *(const short8*)&As[wr * 32 + lr][kc * 32 + lk];
    short8 a1 = *(const short8*)&As[wr * 32 + 16 + lr][kc * 32 + lk];
#pragma unroll
    for (int j = 0; j < 4; j++) {
      short8 bf = *(const short8*)&Bs[wc * 64 + j * 16 + lr][kc * 32 + lk];
      acc1[0][j] = __builtin_amdgcn_mfma_f32_16x16x32_bf16(a0, bf, acc1[0][j], 0, 0, 0);
      acc1[1][j] = __builtin_amdgcn_mfma_f32_16x16x32_bf16(a1, bf, acc1[1][j], 0, 0, 0);
    }
  }
  // residual + stats
#pragma unroll
  for (int i = 0; i < 2; i++) {
#pragma unroll
    for (int r = 0; r < 4; r++) {
      int rloc = wr * 32 + i * 16 + lq * 4 + r;
      int grow = m0 + rloc;
      float p1 = 0.f, p2 = 0.f;
#pragma unroll
      for (int j = 0; j < 4; j++) {
        int gn = wc * 64 + j * 16 + lr;
        float v = acc1[i][j][r] + ob[gn] + h[(long)grow * 128 + gn];
        acc1[i][j][r] = v;
        p1 += v;
        p2 += v * v;
        if (nb == 0) h2[(long)grow * 128 + gn] = v;
      }
      atomicAdd(&stats[rloc][0], p1);
      atomicAdd(&stats[rloc][1], p2);
    }
  }
  __syncthreads();
  // LN -> As (reuse)
#pragma unroll
  for (int i = 0; i < 2; i++) {
#pragma unroll
    for (int r = 0; r < 4; r++) {
      int rloc = wr * 32 + i * 16 + lq * 4 + r;
      float mu = stats[rloc][0] * 0.0078125f;
      float var = stats[rloc][1] * 0.0078125f - mu * mu;
      float rs = rsqrtf(var + 1e-5f);
#pragma unroll
      for (int j = 0; j < 4; j++) {
        int gn = wc * 64 + j * 16 + lr;
        float y = (acc1[i][j][r] - mu) * rs * g2[gn] + b2[gn];
        As[rloc][gn] = f2bf(y);
      }
    }
  }
  __syncthreads();
  short8 af2[2][4];
#pragma unroll
  for (int i = 0; i < 2; i++)
#pragma unroll
    for (int kc = 0; kc < 4; kc++)
      af2[i][kc] = *(const short8*)&As[wr * 32 + i * 16 + lr][kc * 32 + lk];
  // ff1 slice: 4 sub-tiles of 64 cols
#pragma unroll 1
  for (int t = 0; t < 4; t++) {
    int n0t = nb * 256 + t * 64;
    __syncthreads();
#pragma unroll
    for (int u4 = 0; u4 < 4; u4++) {
      int u = tid + u4 * 256;
      int r = u >> 4, c8 = (u & 15) * 8;
      *(short8*)&Bs[r][c8] = *(const short8*)(W1T + (long)(n0t + r) * 128 + c8);
    }
    __syncthreads();
    floatx4 acc2[2][2];
#pragma unroll
    for (int i = 0; i < 2; i++)
#pragma unroll
      for (int j = 0; j < 2; j++) acc2[i][j] = (floatx4){0.f, 0.f, 0.f, 0.f};
#pragma unroll
    for (int kc = 0; kc < 4; kc++) {
#pragma unroll
      for (int j = 0; j < 2; j++) {
        short8 bf = *(const short8*)&Bs[wc * 32 + j * 16 + lr][kc * 32 + lk];
        acc2[0][j] = __builtin_amdgcn_mfma_f32_16x16x32_bf16(af2[0][kc], bf, acc2[0][j], 0, 0, 0);
        acc2[1][j] = __builtin_amdgcn_mfma_f32_16x16x32_bf16(af2[1][kc], bf, acc2[1][j], 0, 0, 0);
      }
    }
#pragma unroll
    for (int i = 0; i < 2; i++) {
#pragma unroll
      for (int j = 0; j < 2; j++) {
        int gng = n0t + wc * 32 + j * 16 + lr;
#pragma unroll
        for (int r = 0; r < 4; r++) {
          int grow = m0 + wr * 32 + i * 16 + lq * 4 + r;
          float v = gelu_f(acc2[i][j][r] + b1[gng]);
          gbf[(long)grow * 512 + gng] = f2bf(v);
        }
      }
    }
  }
}

// ---------------------------------------------------------------------------
// blockC: g@ff2 + ff2_b + h2 -> h3 (f32, nb==0) ; LN1next(h3) ; @qkv slice
// -> qkvb.  grid (98, 2) (or (98,1) with last=1 for the final layer).
// ---------------------------------------------------------------------------
__global__ __launch_bounds__(256) void blockC_k(
    const u16* __restrict__ gbf, const u16* __restrict__ W2T,
    const float* __restrict__ b2f, const float* __restrict__ h2,
    const float* __restrict__ g1, const float* __restrict__ b1,
    const u16* __restrict__ WqT, const float* __restrict__ bq,
    float* __restrict__ h3, u16* __restrict__ qkvo, int last) {
  __shared__ u16 As[64][136];
  __shared__ u16 Bs[128][136];
  __shared__ float stats[64][2];
  const int tid = threadIdx.x, w = tid >> 6, lane = tid & 63;
  const int m0 = blockIdx.x * 64, nb = blockIdx.y;
  const int wr = w & 1, wc = w >> 1;
  const int lr = lane & 15, lq = lane >> 4, lk = lq * 8;
  if (tid < 128) stats[tid >> 1][tid & 1] = 0.f;
  floatx4 acc1[2][4];
#pragma unroll
  for (int i = 0; i < 2; i++)
#pragma unroll
    for (int j = 0; j < 4; j++) acc1[i][j] = (floatx4){0.f, 0.f, 0.f, 0.f};
#pragma unroll 1
  for (int kb = 0; kb < 4; kb++) {
    __syncthreads();
#pragma unroll
    for (int t = 0; t < 4; t++) {
      int u = tid + t * 256;
      int r = u >> 4, c8 = (u & 15) * 8;
      *(short8*)&As[r][c8] = *(const short8*)(gbf + (long)(m0 + r) * 512 + kb * 128 + c8);
    }
#pragma unroll
    for (int t = 0; t < 8; t++) {
      int u = tid + t * 256;
      int r = u >> 4, c8 = (u & 15) * 8;
      *(short8*)&Bs[r][c8] = *(const short8*)(W2T + (long)r * 512 + kb * 128 + c8);
    }
    __syncthreads();
#pragma unroll
    for (int kc = 0; kc < 4; kc++) {
      short8 a0 = *(const short8*)&As[wr * 32 + lr][kc * 32 + lk];
      short8 a1 = *(const short8*)&As[wr * 32 + 16 + lr][kc * 32 + lk];
#pragma unroll
      for (int j = 0; j < 4; j++) {
        short8 bf = *(const short8*)&Bs[wc * 64 + j * 16 + lr][kc * 32 + lk];
        acc1[0][j] = __builtin_amdgcn_mfma_f32_16x16x32_bf16(a0, bf, acc1[0][j], 0, 0, 0);
        acc1[1][j] = __builtin_amdgcn_mfma_f32_16x16x32_bf16(a1, bf, acc1[1][j], 0, 0, 0);
      }
    }
  }
#pragma unroll
  for (int i = 0; i < 2; i++) {
#pragma unroll
    for (int r = 0; r < 4; r++) {
      int rloc = wr * 32 + i * 16 + lq * 4 + r;
      int grow = m0 + rloc;
      float p1 = 0.f, p2 = 0.f;
#pragma unroll
      for (int j = 0; j < 4; j++) {
        int gn = wc * 64 + j * 16 + lr;
        float v = acc1[i][j][r] + b2f[gn] + h2[(long)grow * 128 + gn];
        acc1[i][j][r] = v;
        p1 += v;
        p2 += v * v;
        if (nb == 0) h3[(long)grow * 128 + gn] = v;
      }
      if (!last) {
        atomicAdd(&stats[rloc][0], p1);
        atomicAdd(&stats[rloc][1], p2);
      }
    }
  }
  if (last) return;
  __syncthreads();
#pragma unroll
  for (int i = 0; i < 2; i++) {
#pragma unroll
    for (int r = 0; r < 4; r++) {
      int rloc = wr * 32 + i * 16 + lq * 4 + r;
      float mu = stats[rloc][0] * 0.0078125f;
      float var = stats[rloc][1] * 0.0078125f - mu * mu;
      float rs = rsqrtf(var + 1e-5f);
#pragma unroll
      for (int j = 0; j < 4; j++) {
        int gn = wc * 64 + j * 16 + lr;
        float y = (acc1[i][j][r] - mu) * rs * g1[gn] + b1[gn];
        As[rloc][gn] = f2bf(y);
      }
    }
  }
  __syncthreads();
  short8 af2[2][4];
#pragma unroll
  for (int i = 0; i < 2; i++)
#pragma unroll
    for (int kc = 0; kc < 4; kc++)
      af2[i][kc] = *(const short8*)&As[wr * 32 + i * 16 + lr][kc * 32 + lk];
#pragma unroll 1
  for (int t = 0; t < 3; t++) {
    int n0t = nb * 192 + t * 64;
    __syncthreads();
#pragma unroll
    for (int u4 = 0; u4 < 4; u4++) {
      int u = tid + u4 * 256;
      int r = u >> 4, c8 = (u & 15) * 8;
      *(short8*)&Bs[r][c8] = *(const short8*)(WqT + (long)(n0t + r) * 128 + c8);
    }
    __syncthreads();
    floatx4 acc2[2][2];
#pragma unroll
    for (int i = 0; i < 2; i++)
#pragma unroll
      for (int j = 0; j < 2; j++) acc2[i][j] = (floatx4){0.f, 0.f, 0.f, 0.f};
#pragma unroll
    for (int kc = 0; kc < 4; kc++) {
#pragma unroll
      for (int j = 0; j < 2; j++) {
        short8 bf = *(const short8*)&Bs[wc * 32 + j * 16 + lr][kc * 32 + lk];
        acc2[0][j] = __builtin_amdgcn_mfma_f32_16x16x32_bf16(af2[0][kc], bf, acc2[0][j], 0, 0, 0);
        acc2[1][j] = __builtin_amdgcn_mfma_f32_16x16x32_bf16(af2[1][kc], bf, acc2[1][j], 0, 0, 0);
      }
    }
#pragma unroll
    for (int i = 0; i < 2; i++) {
#pragma unroll
      for (int j = 0; j < 2; j++) {
        int gng = n0t + wc * 32 + j * 16 + lr;
#pragma unroll
        for (int r = 0; r < 4; r++) {
          int grow = m0 + wr * 32 + i * 16 + lq * 4 + r;
          float v = acc2[i][j][r] + bq[gng];
          qkvo[(long)grow * 384 + gng] = f2bf(v);
        }
      }
    }
  }
}

// ---------------------------------------------------------------------------
// Fused attention for non-kNN layers.
// ---------------------------------------------------------------------------
__global__ __launch_bounds__(256) void attn_k(const u16* __restrict__ qkv,
                                              u16* __restrict__ obf) {
  __shared__ u16 qs[32][136];
  __shared__ float sc[32][228];
  __shared__ u16 P[32][232];
  __shared__ u16 Vs[128][40];
  const int tid = threadIdx.x, w = tid >> 6, lane = tid & 63;
  const int b = blockIdx.y, n0 = blockIdx.x * 28;
  const u16* qb = qkv + (long)b * 196 * 384;
  {
    int r = tid >> 3, c0 = (tid & 7) * 16;
    short8 z = {0, 0, 0, 0, 0, 0, 0, 0};
    short8 v0 = z, v1 = z;
    if (r < 28) {
      const u16* src = qb + (long)(n0 + r) * 384 + c0;
      v0 = *(const short8*)src;
      v1 = *(const short8*)(src + 8);
    }
    *(short8*)&qs[r][c0] = v0;
    *(short8*)&qs[r][c0 + 8] = v1;
  }
  __syncthreads();
  const int lr = lane & 15, lq = lane >> 4, lk = lq * 8;
  short8 qf[2][4];
#pragma unroll
  for (int m = 0; m < 2; m++)
#pragma unroll
    for (int kc = 0; kc < 4; kc++)
      qf[m][kc] = *(const short8*)&qs[m * 16 + lr][kc * 32 + lk];

  const u16* kb = qb + 128;
#pragma unroll 1
  for (int c = w; c < 13; c += 4) {
    int key0 = c * 16;
    short8 kf[4];
    const u16* kp = kb + (long)(key0 + lr) * 384;
#pragma unroll
    for (int kc = 0; kc < 4; kc++) kf[kc] = *(const short8*)(kp + kc * 32 + lk);
#pragma unroll
    for (int m = 0; m < 2; m++) {
      floatx4 acc = {0.f, 0.f, 0.f, 0.f};
#pragma unroll
      for (int kc = 0; kc < 4; kc++)
        acc = __builtin_amdgcn_mfma_f32_16x16x32_bf16(qf[m][kc], kf[kc], acc, 0, 0, 0);
#pragma unroll
      for (int j = 0; j < 4; j++) sc[m * 16 + lq * 4 + j][key0 + lr] = acc[j];
    }
  }
  __syncthreads();
  {
    int r = tid >> 3, j0 = (tid & 7) * 28;
    if (r < 28) {
      float v[28];
      float mx = -1e30f;
#pragma unroll
      for (int i = 0; i < 28; i++) {
        int j = j0 + i;
        v[i] = (j < 196) ? sc[r][j] * ATT_SCALE : -1e30f;
        mx = fmaxf(mx, v[i]);
      }
#pragma unroll
      for (int m = 1; m <= 4; m <<= 1) mx = fmaxf(mx, __shfl_xor(mx, m));
      float s = 0.f;
#pragma unroll
      for (int i = 0; i < 28; i++) {
        v[i] = (j0 + i < 196) ? expf(v[i] - mx) : 0.f;
        s += v[i];
      }
#pragma unroll
      for (int m = 1; m <= 4; m <<= 1) s += __shfl_xor(s, m);
      float inv = 1.f / s;
#pragma unroll
      for (int i = 0; i < 28; i++) P[r][j0 + i] = f2bf(v[i] * inv);
    } else {
#pragma unroll
      for (int i = 0; i < 28; i++) P[r][j0 + i] = 0;
    }
  }
  __syncthreads();
  const int mtile = w & 1, nh = w >> 1;
  floatx4 acc[4];
#pragma unroll
  for (int t = 0; t < 4; t++) acc[t] = (floatx4){0.f, 0.f, 0.f, 0.f};
  const u16* vb = qb + 256;
#pragma unroll 1
  for (int kc = 0; kc < 7; kc++) {
    {
      int tok = tid >> 3, d0 = (tid & 7) * 16;
      int gt = kc * 32 + tok;
      short8 z = {0, 0, 0, 0, 0, 0, 0, 0};
      short8 v0 = z, v1 = z;
      if (gt < 196) {
        const u16* vp = vb + (long)gt * 384 + d0;
        v0 = *(const short8*)vp;
        v1 = *(const short8*)(vp + 8);
      }
      u16 tmp[16];
      *(short8*)tmp = v0;
      *(short8*)(tmp + 8) = v1;
#pragma unroll
      for (int i = 0; i < 16; i++) Vs[d0 + i][tok] = tmp[i];
    }
    __syncthreads();
    short8 pf = *(const short8*)&P[mtile * 16 + lr][kc * 32 + lk];
#pragma unroll
    for (int t = 0; t < 4; t++) {
      short8 vf = *(const short8*)&Vs[nh * 64 + t * 16 + lr][lk];
      acc[t] = __builtin_amdgcn_mfma_f32_16x16x32_bf16(pf, vf, acc[t], 0, 0, 0);
    }
    __syncthreads();
  }
#pragma unroll
  for (int t = 0; t < 4; t++) {
    int gn = nh * 64 + t * 16 + lr;
#pragma unroll
    for (int r = 0; r < 4; r++) {
      int rloc = mtile * 16 + lq * 4 + r;
      if (rloc < 28) obf[((long)b * 196 + n0 + rloc) * 128 + gn] = f2bf(acc[t][r]);
    }
  }
}

// ---------------------------------------------------------------------------
// weight convert + transpose
// ---------------------------------------------------------------------------
__global__ __launch_bounds__(256) void cvtw_k(
    const float* __restrict__ pw, const float* __restrict__ qw,
    const float* __restrict__ ow, const float* __restrict__ f1,
    const float* __restrict__ f2, u16* __restrict__ wbf) {
  int idx = blockIdx.x * 256 + threadIdx.x;
  float v;
  if (idx < 98304) {
    int n = idx / 768, k = idx % 768;
    v = pw[k * 128 + n];
  } else if (idx < 442368) {
    int rel = idx - 98304;
    int i = rel / 49152, r = rel % 49152, n = r / 128, k = r % 128;
    v = qw[((long)i * 128 + k) * 384 + n];
  } else if (idx < 557056) {
    int rel = idx - 442368;
    int i = rel / 16384, r = rel % 16384, n = r / 128, k = r % 128;
    v = ow[((long)i * 128 + k) * 128 + n];
  } else if (idx < 1015808) {
    int rel = idx - 557056;
    int i = rel / 65536, r = rel % 65536, n = r / 128, k = r % 128;
    v = f1[((long)i * 128 + k) * 512 + n];
  } else {
    int rel = idx - 1015808;
    int i = rel / 65536, r = rel % 65536, n = r / 512, k = r % 512;
    v = f2[((long)i * 512 + k) * 128 + n];
  }
  wbf[idx] = f2bf(v);
}

__global__ __launch_bounds__(256) void patchify_k(const float* __restrict__ x,
                                                  u16* __restrict__ p) {
  long idx = (long)blockIdx.x * 256 + threadIdx.x;
  int f = (int)(idx % 768);
  long bn = idx / 768;
  int n = (int)(bn % 196);
  int b = (int)(bn / 196);
  int c = f >> 8, ri = (f >> 4) & 15, cj = f & 15;
  int ph = n / 14, pw = n % 14;
  float v = x[(((long)b * 3 + c) * 224 + ph * 16 + ri) * 224 + pw * 16 + cj];
  p[idx] = f2bf(v);
}

// joint softmax over [32 memory scores | 196 local sims]  (kNN layer)
__global__ __launch_bounds__(256) void knn_softmax_k(
    const float* __restrict__ sim, const float* __restrict__ mvals,
    u16* __restrict__ p, float* __restrict__ am) {
  int row = blockIdx.x * 4 + (threadIdx.x >> 6);
  int lane = threadIdx.x & 63;
  const float* sr = sim + (long)row * 224;
  float v[4];
#pragma unroll
  for (int t = 0; t < 4; t++) {
    int j = t * 64 + lane;
    v[t] = (j < 196) ? sr[j] : -1e30f;
  }
  float mvv = (lane < 32) ? mvals[(long)row * 32 + lane] : -1e30f;
  float mx = wmaxr(fmaxf(fmaxf(fmaxf(v[0], v[1]), fmaxf(v[2], v[3])), mvv));
  float e[4], s = 0.f;
#pragma unroll
  for (int t = 0; t < 4; t++) {
    int j = t * 64 + lane;
    e[t] = (j < 196) ? expf(v[t] - mx) : 0.f;
    s += e[t];
  }
  float em = (lane < 32) ? expf(mvv - mx) : 0.f;
  s = wsum(s + em);
  float inv = 1.f / s;
  u16* pr = p + (long)row * 224;
#pragma unroll
  for (int t = 0; t < 4; t++) {
    int j = t * 64 + lane;
    if (j < 224) pr[j] = f2bf(e[t] * inv);
  }
  if (lane < 32) am[(long)row * 32 + lane] = em * inv;
}

// ---------------------------------------------------------------------------
// msim + streaming top-6 per 64-key lane stream (768 candidates/row).
// ---------------------------------------------------------------------------
__global__ __launch_bounds__(256) void msim_topk_k(
    const u16* __restrict__ qkv, const float* __restrict__ knnk,
    unsigned* __restrict__ cand) {
  __shared__ u16 qs[64][136];
  const int tid = threadIdx.x, w = tid >> 6, lane = tid & 63;
  const int b = blockIdx.z, n0 = blockIdx.y * 49, kq0 = blockIdx.x * 1024;
  const u16* qb = qkv + (long)b * 196 * 384;
#pragma unroll
  for (int t = 0; t < 4; t++) {
    int task = tid + t * 256;
    int r = task >> 4, c8 = (task & 15) * 8;
    short8 v = {0, 0, 0, 0, 0, 0, 0, 0};
    if (r < 49) v = *(const short8*)(qb + (long)(n0 + r) * 384 + c8);
    *(short8*)&qs[r][c8] = v;
  }
  __syncthreads();
  const int lr = lane & 15, lq = lane >> 4, lk = lq * 8;
  short8 qf[4][4];
#pragma unroll
  for (int s = 0; s < 4; s++)
#pragma unroll
    for (int kc = 0; kc < 4; kc++)
      qf[s][kc] = *(const short8*)&qs[s * 16 + lr][kc * 32 + lk];

  unsigned st[4][6];
#pragma unroll
  for (int s = 0; s < 4; s++)
#pragma unroll
    for (int t = 0; t < 6; t++) st[s][t] = 0u;

  const float* kbase = knnk + ((long)b * 8192 + kq0 + lr) * 128 + lk;

  float4 raw[8];
  {
    const float* kp = kbase + (long)(w * 16) * 128;
#pragma unroll
    for (int kc = 0; kc < 4; kc++) {
      raw[kc * 2] = *(const float4*)(kp + kc * 32);
      raw[kc * 2 + 1] = *(const float4*)(kp + kc * 32 + 4);
    }
  }
#pragma unroll 1
  for (int c = 0; c < 16; c++) {
    float4 nraw[8];
    if (c < 15) {
      const float* kp = kbase + (long)(((c + 1) * 4 + w) * 16) * 128;
#pragma unroll
      for (int kc = 0; kc < 4; kc++) {
        nraw[kc * 2] = *(const float4*)(kp + kc * 32);
        nraw[kc * 2 + 1] = *(const float4*)(kp + kc * 32 + 4);
      }
    }
    short8 kf[4];
#pragma unroll
    for (int kc = 0; kc < 4; kc++) {
      int4 iv;
      iv.x = (int)bfpack(raw[kc * 2].x, raw[kc * 2].y);
      iv.y = (int)bfpack(raw[kc * 2].z, raw[kc * 2].w);
      iv.z = (int)bfpack(raw[kc * 2 + 1].x, raw[kc * 2 + 1].y);
      iv.w = (int)bfpack(raw[kc * 2 + 1].z, raw[kc * 2 + 1].w);
      kf[kc] = *(short8*)&iv;
    }
    const int kb = kq0 + (c * 4 + w) * 16 + lq * 4;
#pragma unroll
    for (int s = 0; s < 4; s++) {
      floatx4 acc = {0.f, 0.f, 0.f, 0.f};
#pragma unroll
      for (int kc = 0; kc < 4; kc++)
        acc = __builtin_amdgcn_mfma_f32_16x16x32_bf16(kf[kc], qf[s][kc], acc, 0, 0, 0);
#pragma unroll
      for (int r = 0; r < 4; r++) {
        unsigned u = __float_as_uint(acc[r]);
        unsigned mono = u ^ ((unsigned)((int)u >> 31) | 0x80000000u);
        unsigned x = (mono & 0xFFFFE000u) | (unsigned)(kb + r);
#pragma unroll
        for (int t = 0; t < 6; t++) {
          unsigned mx = max(st[s][t], x);
          x = min(st[s][t], x);
          st[s][t] = mx;
        }
      }
    }
    if (c < 15) {
#pragma unroll
      for (int i = 0; i < 8; i++) raw[i] = nraw[i];
    }
  }
#pragma unroll
  for (int s = 0; s < 4; s++) {
    int rloc = s * 16 + lr;
    if (rloc < 49) {
      unsigned* dst = cand + ((long)b * 196 + n0 + rloc) * 768 + blockIdx.x * 96 + w * 24 + lq * 6;
#pragma unroll
      for (int t = 0; t < 6; t++) dst[t] = st[s][t];
    }
  }
}

// merge 768 candidates/row -> exact top-32 of the candidate set
__global__ __launch_bounds__(256) void topk_merge_k(
    const unsigned* __restrict__ cand, float* __restrict__ mvals,
    int* __restrict__ midx) {
  int row = blockIdx.x * 4 + (threadIdx.x >> 6);
  int lane = threadIdx.x & 63;
  const unsigned* cr = cand + (long)row * 768;
  unsigned c[12];
#pragma unroll
  for (int t = 0; t < 12; t++) c[t] = cr[t * 64 + lane];
  float* mv = mvals + (long)row * 32;
  int* mi = midx + (long)row * 32;
  for (int r = 0; r < 32; r++) {
    unsigned lm = c[0];
#pragma unroll
    for (int t = 1; t < 12; t++) lm = max(lm, c[t]);
    unsigned gm = lm;
#pragma unroll
    for (int m = 32; m >= 1; m >>= 1) gm = max(gm, (unsigned)__shfl_xor((int)gm, m));
    bool has = false;
#pragma unroll
    for (int t = 0; t < 12; t++)
      if (!has && c[t] == gm) {
        c[t] = 0u;
        has = true;
      }
    if (has) {
      mv[r] = unpack_sc(gm) * ATT_SCALE;
      mi[r] = (int)(gm & 0x1FFFu);
    }
  }
}

// o32[row][d] = sum_k am[k] * knn_v[b][midx[k]][d]
__global__ __launch_bounds__(256) void knn_gather_k(
    const float* __restrict__ am, const int* __restrict__ ix,
    const float* __restrict__ kv, float* __restrict__ o32) {
  int row = blockIdx.x * 4 + (threadIdx.x >> 6);
  int lane = threadIdx.x & 63;
  int b = row / 196;
  const float* vb = kv + (long)b * 8192 * 128;
  const float* ar = am + (long)row * 32;
  const int* xr = ix + (long)row * 32;
  float a0 = 0.f, a1 = 0.f;
#pragma unroll 4
  for (int k = 0; k < 32; k++) {
    float wv = ar[k];
    int id = xr[k];
    float2 v = *(const float2*)&vb[(long)id * 128 + lane * 2];
    a0 += wv * v.x;
    a1 += wv * v.y;
  }
  float2 o;
  o.x = a0;
  o.y = a1;
  *(float2*)&o32[(long)row * 128 + lane * 2] = o;
}

// final LN + token-mean + head GEMM
__global__ __launch_bounds__(256) void final_k(
    const float* __restrict__ h, const float* __restrict__ g,
    const float* __restrict__ bb, const float* __restrict__ hw,
    const float* __restrict__ hb, float* __restrict__ out) {
  __shared__ float fw[4][128];
  __shared__ float feats[128];
  int tid = threadIdx.x, w = tid >> 6, lane = tid & 63;
  int b = blockIdx.x;
  float2 gv = *(const float2*)&g[lane * 2];
  float2 bv = *(const float2*)&bb[lane * 2];
  float a0 = 0.f, a1 = 0.f;
  for (int r = w; r < 196; r += 4) {
    float2 x = *(const float2*)&h[((long)b * 196 + r) * 128 + lane * 2];
    float mu = wsum(x.x + x.y) * 0.0078125f;
    float d0 = x.x - mu, d1 = x.y - mu;
    float var = wsum(d0 * d0 + d1 * d1) * 0.0078125f;
    float rs = 1.f / sqrtf(var + 1e-5f);
    a0 += d0 * rs * gv.x + bv.x;
    a1 += d1 * rs * gv.y + bv.y;
  }
  fw[w][lane * 2] = a0;
  fw[w][lane * 2 + 1] = a1;
  __syncthreads();
  if (tid < 128) feats[tid] = (fw[0][tid] + fw[1][tid] + fw[2][tid] + fw[3][tid]) * (1.f / 196.f);
  __syncthreads();
  for (int o = tid; o < 1000; o += 256) {
    float acc = hb[o];
    for (int d = 0; d < 128; d++) acc += feats[d] * hw[d * 1000 + o];
    out[(long)b * 1000 + o] = acc;
  }
}

// ---------------------------------------------------------------------------
extern "C" void kernel_launch(void* const* d_in, const int* in_sizes, int n_in,
                              void* d_out, int out_size, void* d_ws, size_t ws_size,
                              hipStream_t stream) {
  (void)in_sizes; (void)n_in; (void)out_size; (void)ws_size;
  const float* x       = (const float*)d_in[0];
  const float* patch_w = (const float*)d_in[1];
  const float* patch_b = (const float*)d_in[2];
  const float* ln1_g   = (const float*)d_in[3];
  const float* ln1_b   = (const float*)d_in[4];
  const float* qkv_w   = (const float*)d_in[5];
  const float* qkv_b   = (const float*)d_in[6];
  const float* out_w   = (const float*)d_in[7];
  const float* out_b   = (const float*)d_in[8];
  const float* ln2_g   = (const float*)d_in[9];
  const float* ln2_b   = (const float*)d_in[10];
  const float* ff1_w   = (const float*)d_in[11];
  const float* ff1_b   = (const float*)d_in[12];
  const float* ff2_w   = (const float*)d_in[13];
  const float* ff2_b   = (const float*)d_in[14];
  const float* lnf_g   = (const float*)d_in[15];
  const float* lnf_b   = (const float*)d_in[16];
  const float* knn_k   = (const float*)d_in[17];
  const float* knn_v   = (const float*)d_in[18];
  const float* head_w  = (const float*)d_in[19];
  const float* head_b  = (const float*)d_in[20];

  char* ws = (char*)d_ws;
  size_t off = 0;
  u16* wbf = (u16*)(ws + off);        off += 2949120;
  u16* p_bf = (u16*)(ws + off);       off += 9633792;
  float* h = (float*)(ws + off);      off += 3211264;
  float* h2 = (float*)(ws + off);     off += 3211264;
  u16* qkvb = (u16*)(ws + off);       off += 4816896;
  u16* g_bf = (u16*)(ws + off);       off += 6422528;
  u16* o_bf = (u16*)(ws + off);       off += 1605632;
  float* o32 = (float*)(ws + off);    off += 3211264;
  float* simf = (float*)(ws + off);   off += 5619712;
  u16* pbf = (u16*)(ws + off);        off += 2809856;
  unsigned* cand = (unsigned*)(ws + off); off += 19267584;
  float* mvals = (float*)(ws + off);  off += 802816;
  int* midx = (int*)(ws + off);       off += 802816;
  float* amf = (float*)(ws + off);    off += 802816;

  const int qkvT = 98304, outT = 442368, ff1T = 557056, ff2T = 1015808;

  dim3 blk(256);
  cvtw_k<<<5760, blk, 0, stream>>>(patch_w, qkv_w, out_w, ff1_w, ff2_w, wbf);
  patchify_k<<<18816, blk, 0, stream>>>(x, p_bf);
  gemm_k<0, false><<<dim3(49, 2, 1), blk, 0, stream>>>(
      p_bf, 768, 0, wbf, 768, 0, 768, patch_b, nullptr, 0, h, 128, 0, 6272, 128, 768, 1.f);
  // layer-0 qkv
  lngemm_k<<<dim3(49, 6), blk, 0, stream>>>(
      h, ln1_g, ln1_b, wbf + qkvT, qkv_b, qkvb, 384, 384);

  for (int i = 0; i < 7; i++) {
    if (i == 6) {
      msim_topk_k<<<dim3(8, 4, 32), blk, 0, stream>>>(qkvb, knn_k, cand);
      topk_merge_k<<<1568, blk, 0, stream>>>(cand, mvals, midx);
      gemm_k<4, false><<<dim3(2, 4, 32), blk, 0, stream>>>(
          qkvb, 384, (long)196 * 384, qkvb + 128, 384, (long)196 * 384, 128,
          nullptr, nullptr, 0, simf, 224, (long)196 * 224, 196, 196, 128, ATT_SCALE);
      knn_softmax_k<<<1568, blk, 0, stream>>>(simf, mvals, pbf, amf);
      knn_gather_k<<<1568, blk, 0, stream>>>(amf, midx, knn_v, o32);
      gemm_k<5, true><<<dim3(2, 2, 32), blk, 0, stream>>>(
          pbf, 224, (long)196 * 224, qkvb + 256, 384, (long)196 * 384, 196,
          nullptr, o32, (long)196 * 128, o_bf, 128, (long)196 * 128, 196, 128, 224, 1.f);
    } else {
      attn_k<<<dim3(7, 32), blk, 0, stream>>>(qkvb, o_bf);
    }
    blockB_k<<<dim3(98, 2), blk, 0, stream>>>(
        o_bf, wbf + outT + i * 16384, out_b + i * 128, h,
        ln2_g + i * 128, ln2_b + i * 128, wbf + ff1T + i * 65536, ff1_b + i * 512,
        h2, g_bf);
    if (i < 6) {
      blockC_k<<<dim3(98, 2), blk, 0, stream>>>(
          g_bf, wbf + ff2T + i * 65536, ff2_b + i * 128, h2,
          ln1_g + (i + 1) * 128, ln1_b + (i + 1) * 128,
          wbf + qkvT + (i + 1) * 49152, qkv_b + (i + 1) * 384, h, qkvb, 0);
    } else {
      blockC_k<<<dim3(98, 1), blk, 0, stream>>>(
          g_bf, wbf + ff2T + i * 65536, ff2_b + i * 128, h2,
          ln1_g, ln1_b, wbf + qkvT, qkv_b, h, qkvb, 1);
    }
  }
  final_k<<<32, blk, 0, stream>>>(h, lnf_g, lnf_b, head_w, head_b, (float*)d_out);
}